// Round 1
// baseline (1464.561 us; speedup 1.0000x reference)
//
#include <hip/hip_runtime.h>
#include <hip/hip_bf16.h>

#define B_ 2
#define S_ 2048
#define D_ 1024
#define H_ 16
#define DK_ 64

// ---------------------------------------------------------------------------
// Kernel 1: quantum transform  y = tanh(x@W1 + b1)@W2 + b2  on rows of 64.
// in:  [B, S, H, DK] (rows of 64 contiguous)
// out: [B, H, S, DK] (head-major, for attention)
// ---------------------------------------------------------------------------
__global__ __launch_bounds__(256) void quantum_kernel(
    const float* __restrict__ x,
    const float* __restrict__ W1, const float* __restrict__ b1,
    const float* __restrict__ W2, const float* __restrict__ b2,
    float* __restrict__ out) {
  __shared__ float w1s[64 * 64];
  __shared__ float w2s[64 * 64];
  __shared__ float b1s[64], b2s[64];
  __shared__ float xs[4][64];
  __shared__ float ts[4][64];

  const int tid = threadIdx.x;

  // stage weights (coalesced float4)
  const float4* W14 = (const float4*)W1;
  const float4* W24 = (const float4*)W2;
  float4* w1s4 = (float4*)w1s;
  float4* w2s4 = (float4*)w2s;
#pragma unroll
  for (int t = 0; t < 4; ++t) {
    w1s4[tid + 256 * t] = W14[tid + 256 * t];
    w2s4[tid + 256 * t] = W24[tid + 256 * t];
  }
  if (tid < 64) {
    b1s[tid] = b1[tid];
    b2s[tid] = b2[tid];
  }
  __syncthreads();

  const int j = tid & 63;   // output dim
  const int rl = tid >> 6;  // local row (= wave id)
  const int ngroups = (B_ * S_ * H_) / 4;
  float* xs_flat = &xs[0][0];

  for (int g = blockIdx.x; g < ngroups; g += gridDim.x) {
    const int r0 = g * 4;
    // load 4 consecutive rows (256 consecutive floats), coalesced
    xs_flat[tid] = x[(size_t)r0 * 64 + tid];
    __syncthreads();

    // phase 1: tmp = tanh(x @ W1 + b1)
    float a0 = 0.f, a1 = 0.f, a2 = 0.f, a3 = 0.f;
#pragma unroll
    for (int i = 0; i < 64; i += 4) {
      a0 += xs[rl][i + 0] * w1s[(i + 0) * 64 + j];
      a1 += xs[rl][i + 1] * w1s[(i + 1) * 64 + j];
      a2 += xs[rl][i + 2] * w1s[(i + 2) * 64 + j];
      a3 += xs[rl][i + 3] * w1s[(i + 3) * 64 + j];
    }
    float tm = tanhf((a0 + a1) + (a2 + a3) + b1s[j]);
    ts[rl][j] = tm;
    __syncthreads();

    // phase 2: y = tmp @ W2 + b2
    float c0 = 0.f, c1 = 0.f, c2 = 0.f, c3 = 0.f;
#pragma unroll
    for (int i = 0; i < 64; i += 4) {
      c0 += ts[rl][i + 0] * w2s[(i + 0) * 64 + j];
      c1 += ts[rl][i + 1] * w2s[(i + 1) * 64 + j];
      c2 += ts[rl][i + 2] * w2s[(i + 2) * 64 + j];
      c3 += ts[rl][i + 3] * w2s[(i + 3) * 64 + j];
    }
    float y = (c0 + c1) + (c2 + c3) + b2s[j];

    // row r0+rl -> (b, s, h); out layout [B, H, S, DK]
    const int row = r0 + rl;
    const int b = row >> 15;          // / (S*H) = 32768
    const int rem = row & 32767;
    const int s = rem >> 4;           // / H
    const int h = rem & 15;
    out[(((size_t)b * H_ + h) * S_ + s) * DK_ + j] = y;
    // next iteration's xs write is ordered after this phase's ts reads by
    // the phase-1 barrier of the next iteration (different arrays: safe).
  }
}

// ---------------------------------------------------------------------------
// Kernel 2: flash attention, fp32, one thread per q-row.
// qh/kh/vh: [B, H, S, DK]; ctx out: [B, S, H*DK] (GEMM-A layout)
// grid: (B*H, S/256), block 256
// ---------------------------------------------------------------------------
__global__ __launch_bounds__(256) void attn_kernel(
    const float* __restrict__ qh, const float* __restrict__ kh,
    const float* __restrict__ vh, float* __restrict__ ctx) {
  __shared__ float ks[64 * 64];
  __shared__ float vs[64 * 64];

  const int tid = threadIdx.x;
  const int bh = blockIdx.x;  // 0..31
  const int b = bh >> 4, h = bh & 15;
  const int s = blockIdx.y * 256 + tid;  // q row within (b,h)

  // load q row into registers, pre-scaled by (1/sqrt(DK)) * log2(e)
  const float scale = 0.125f * 1.44269504088896340736f;
  const float4* qrow4 = (const float4*)(qh + ((size_t)bh * S_ + s) * DK_);
  float q[64];
#pragma unroll
  for (int i4 = 0; i4 < 16; ++i4) {
    float4 t = qrow4[i4];
    q[i4 * 4 + 0] = t.x * scale;
    q[i4 * 4 + 1] = t.y * scale;
    q[i4 * 4 + 2] = t.z * scale;
    q[i4 * 4 + 3] = t.w * scale;
  }

  float ctxr[64];
#pragma unroll
  for (int d = 0; d < 64; ++d) ctxr[d] = 0.f;
  float m = -1e30f, l = 0.f;

  const float* kbase = kh + (size_t)bh * S_ * DK_;
  const float* vbase = vh + (size_t)bh * S_ * DK_;

  for (int t0 = 0; t0 < S_; t0 += 64) {
    __syncthreads();  // previous tile's reads done before overwrite
    // stage K,V tile: 64 keys x 64 dims each (16 KB each), coalesced
    const float4* k4 = (const float4*)(kbase + (size_t)t0 * 64);
    const float4* v4 = (const float4*)(vbase + (size_t)t0 * 64);
#pragma unroll
    for (int w = 0; w < 4; ++w) {
      ((float4*)ks)[tid + 256 * w] = k4[tid + 256 * w];
      ((float4*)vs)[tid + 256 * w] = v4[tid + 256 * w];
    }
    __syncthreads();

    for (int k = 0; k < 64; ++k) {
      // score = q . k  (LDS broadcast reads, 4 accumulator chains)
      const float4* krow = (const float4*)(ks + k * 64);
      float a0 = 0.f, a1 = 0.f, a2 = 0.f, a3 = 0.f;
#pragma unroll
      for (int i4 = 0; i4 < 16; ++i4) {
        float4 kv = krow[i4];
        a0 += q[i4 * 4 + 0] * kv.x;
        a1 += q[i4 * 4 + 1] * kv.y;
        a2 += q[i4 * 4 + 2] * kv.z;
        a3 += q[i4 * 4 + 3] * kv.w;
      }
      float sc = (a0 + a1) + (a2 + a3);  // already in log2 domain w/ scale

      if (sc > m) {  // rare after warm-up (~log(S) per lane)
        float corr = exp2f(m - sc);
#pragma unroll
        for (int d = 0; d < 64; ++d) ctxr[d] *= corr;
        l *= corr;
        m = sc;
      }
      float p = exp2f(sc - m);
      l += p;

      const float4* vrow = (const float4*)(vs + k * 64);
#pragma unroll
      for (int d4 = 0; d4 < 16; ++d4) {
        float4 vv = vrow[d4];
        ctxr[d4 * 4 + 0] += p * vv.x;
        ctxr[d4 * 4 + 1] += p * vv.y;
        ctxr[d4 * 4 + 2] += p * vv.z;
        ctxr[d4 * 4 + 3] += p * vv.w;
      }
    }
  }

  const float rl = 1.0f / l;
  // ctx layout: [B, S, H*DK] so the output GEMM reads contiguous rows
  float4* outp = (float4*)(ctx + (((size_t)b * S_ + s) * H_ + h) * DK_);
#pragma unroll
  for (int d4 = 0; d4 < 16; ++d4) {
    float4 o;
    o.x = ctxr[d4 * 4 + 0] * rl;
    o.y = ctxr[d4 * 4 + 1] * rl;
    o.z = ctxr[d4 * 4 + 2] * rl;
    o.w = ctxr[d4 * 4 + 3] * rl;
    outp[d4] = o;
  }
}

// ---------------------------------------------------------------------------
// Kernel 3: out = ctx[4096,1024] @ Wo[1024,1024] + bo, fp32 tiled.
// BM=BN=64, BK=16, 256 threads, 4x4 micro-tile per thread.
// grid: (N/64=16, M/64=64)
// ---------------------------------------------------------------------------
__global__ __launch_bounds__(256) void out_gemm(
    const float* __restrict__ A, const float* __restrict__ Wo,
    const float* __restrict__ bo, float* __restrict__ C) {
  __shared__ float As[64][17];  // +1 pad: conflict-free a-reads
  __shared__ float Bs[16][64];

  const int tid = threadIdx.x;
  const int tx = tid & 15, ty = tid >> 4;
  const int m0 = blockIdx.y * 64;
  const int n0 = blockIdx.x * 64;

  float acc[4][4];
#pragma unroll
  for (int i = 0; i < 4; ++i)
#pragma unroll
    for (int jj = 0; jj < 4; ++jj) acc[i][jj] = 0.f;

  for (int k0 = 0; k0 < D_; k0 += 16) {
    __syncthreads();
    // stage A tile 64x16 (scalar LDS stores into padded rows)
    {
      const int r = tid >> 2, kq = tid & 3;
      float4 av = *(const float4*)&A[(size_t)(m0 + r) * D_ + k0 + kq * 4];
      As[r][kq * 4 + 0] = av.x;
      As[r][kq * 4 + 1] = av.y;
      As[r][kq * 4 + 2] = av.z;
      As[r][kq * 4 + 3] = av.w;
    }
    // stage B tile 16x64 (aligned float4)
    {
      const int kk = tid >> 4, cq = tid & 15;
      *(float4*)&Bs[kk][cq * 4] =
          *(const float4*)&Wo[(size_t)(k0 + kk) * D_ + n0 + cq * 4];
    }
    __syncthreads();

#pragma unroll
    for (int kk = 0; kk < 16; ++kk) {
      float a0 = As[ty * 4 + 0][kk];
      float a1 = As[ty * 4 + 1][kk];
      float a2 = As[ty * 4 + 2][kk];
      float a3 = As[ty * 4 + 3][kk];
      float4 bq = *(const float4*)&Bs[kk][tx * 4];
      acc[0][0] += a0 * bq.x; acc[0][1] += a0 * bq.y;
      acc[0][2] += a0 * bq.z; acc[0][3] += a0 * bq.w;
      acc[1][0] += a1 * bq.x; acc[1][1] += a1 * bq.y;
      acc[1][2] += a1 * bq.z; acc[1][3] += a1 * bq.w;
      acc[2][0] += a2 * bq.x; acc[2][1] += a2 * bq.y;
      acc[2][2] += a2 * bq.z; acc[2][3] += a2 * bq.w;
      acc[3][0] += a3 * bq.x; acc[3][1] += a3 * bq.y;
      acc[3][2] += a3 * bq.z; acc[3][3] += a3 * bq.w;
    }
  }

  const float4 bov = *(const float4*)&bo[n0 + tx * 4];
#pragma unroll
  for (int i = 0; i < 4; ++i) {
    float4 o;
    o.x = acc[i][0] + bov.x;
    o.y = acc[i][1] + bov.y;
    o.z = acc[i][2] + bov.z;
    o.w = acc[i][3] + bov.w;
    *(float4*)&C[(size_t)(m0 + ty * 4 + i) * D_ + n0 + tx * 4] = o;
  }
}

// ---------------------------------------------------------------------------
extern "C" void kernel_launch(void* const* d_in, const int* in_sizes, int n_in,
                              void* d_out, int out_size, void* d_ws,
                              size_t ws_size, hipStream_t stream) {
  const float* q = (const float*)d_in[0];
  const float* k = (const float*)d_in[1];
  const float* v = (const float*)d_in[2];
  const float* Wq1 = (const float*)d_in[3];
  const float* bq1 = (const float*)d_in[4];
  const float* Wq2 = (const float*)d_in[5];
  const float* bq2 = (const float*)d_in[6];
  const float* Wk1 = (const float*)d_in[7];
  const float* bk1 = (const float*)d_in[8];
  const float* Wk2 = (const float*)d_in[9];
  const float* bk2 = (const float*)d_in[10];
  const float* Wv1 = (const float*)d_in[11];
  const float* bv1 = (const float*)d_in[12];
  const float* Wv2 = (const float*)d_in[13];
  const float* bv2 = (const float*)d_in[14];
  const float* Wo = (const float*)d_in[15];
  const float* bo = (const float*)d_in[16];
  float* out = (float*)d_out;

  float* ws = (float*)d_ws;
  const size_t TEN = (size_t)B_ * H_ * S_ * DK_;  // 4,194,304
  float* qh = ws;
  float* kh = ws + TEN;
  float* vh = ws + 2 * TEN;
  float* ctx = ws + 3 * TEN;

  quantum_kernel<<<dim3(2048), 256, 0, stream>>>(q, Wq1, bq1, Wq2, bq2, qh);
  quantum_kernel<<<dim3(2048), 256, 0, stream>>>(k, Wk1, bk1, Wk2, bk2, kh);
  quantum_kernel<<<dim3(2048), 256, 0, stream>>>(v, Wv1, bv1, Wv2, bv2, vh);

  attn_kernel<<<dim3(32, 8), 256, 0, stream>>>(qh, kh, vh, ctx);

  out_gemm<<<dim3(16, 64), 256, 0, stream>>>(ctx, Wo, bo, out);
}

// Round 2
// 436.378 us; speedup vs baseline: 3.3562x; 3.3562x over previous
//
#include <hip/hip_runtime.h>

#define B_ 2
#define S_ 2048
#define D_ 1024
#define H_ 16
#define DK_ 64

typedef float f32x4 __attribute__((ext_vector_type(4)));
typedef short bf16x8 __attribute__((ext_vector_type(8)));

static __device__ __forceinline__ unsigned short f2bf(float f) {
  unsigned u = __float_as_uint(f);
  unsigned r = (u + 0x7FFFu + ((u >> 16) & 1u)) >> 16;
  return (unsigned short)r;
}

// ---------------------------------------------------------------------------
// Kernel 1a: quantum transform for q,k.  out bf16 [B, H, S, DK].
// ---------------------------------------------------------------------------
__global__ __launch_bounds__(256) void quantum_kernel(
    const float* __restrict__ x,
    const float* __restrict__ W1, const float* __restrict__ b1,
    const float* __restrict__ W2, const float* __restrict__ b2,
    unsigned short* __restrict__ out) {
  __shared__ float w1s[64 * 64];
  __shared__ float w2s[64 * 64];
  __shared__ float b1s[64], b2s[64];
  __shared__ float xs[4][64];
  __shared__ float ts[4][64];

  const int tid = threadIdx.x;
  const float4* W14 = (const float4*)W1;
  const float4* W24 = (const float4*)W2;
  float4* w1s4 = (float4*)w1s;
  float4* w2s4 = (float4*)w2s;
#pragma unroll
  for (int t = 0; t < 4; ++t) {
    w1s4[tid + 256 * t] = W14[tid + 256 * t];
    w2s4[tid + 256 * t] = W24[tid + 256 * t];
  }
  if (tid < 64) {
    b1s[tid] = b1[tid];
    b2s[tid] = b2[tid];
  }
  __syncthreads();

  const int j = tid & 63;
  const int rl = tid >> 6;
  const int ngroups = (B_ * S_ * H_) / 4;
  float* xs_flat = &xs[0][0];

  for (int g = blockIdx.x; g < ngroups; g += gridDim.x) {
    const int r0 = g * 4;
    xs_flat[tid] = x[(size_t)r0 * 64 + tid];
    __syncthreads();

    float a0 = 0.f, a1 = 0.f, a2 = 0.f, a3 = 0.f;
#pragma unroll
    for (int i = 0; i < 64; i += 4) {
      a0 += xs[rl][i + 0] * w1s[(i + 0) * 64 + j];
      a1 += xs[rl][i + 1] * w1s[(i + 1) * 64 + j];
      a2 += xs[rl][i + 2] * w1s[(i + 2) * 64 + j];
      a3 += xs[rl][i + 3] * w1s[(i + 3) * 64 + j];
    }
    float tm = tanhf((a0 + a1) + (a2 + a3) + b1s[j]);
    ts[rl][j] = tm;
    __syncthreads();

    float c0 = 0.f, c1 = 0.f, c2 = 0.f, c3 = 0.f;
#pragma unroll
    for (int i = 0; i < 64; i += 4) {
      c0 += ts[rl][i + 0] * w2s[(i + 0) * 64 + j];
      c1 += ts[rl][i + 1] * w2s[(i + 1) * 64 + j];
      c2 += ts[rl][i + 2] * w2s[(i + 2) * 64 + j];
      c3 += ts[rl][i + 3] * w2s[(i + 3) * 64 + j];
    }
    float y = (c0 + c1) + (c2 + c3) + b2s[j];

    const int row = r0 + rl;
    const int b = row >> 15;
    const int rem = row & 32767;
    const int s = rem >> 4;
    const int h = rem & 15;
    out[(((size_t)b * H_ + h) * S_ + s) * DK_ + j] = f2bf(y);
  }
}

// ---------------------------------------------------------------------------
// Kernel 1b: quantum transform for v, output TRANSPOSED bf16 [B, H, DK, S].
// One block per (bh, s-block-of-64).
// ---------------------------------------------------------------------------
__global__ __launch_bounds__(256) void quantum_v_kernel(
    const float* __restrict__ x,
    const float* __restrict__ W1, const float* __restrict__ b1,
    const float* __restrict__ W2, const float* __restrict__ b2,
    unsigned short* __restrict__ vt) {
  __shared__ float w1s[64 * 64];
  __shared__ float w2s[64 * 64];
  __shared__ float b1s[64], b2s[64];
  __shared__ float xs[4][64];
  __shared__ float ts[4][64];
  __shared__ float yt[64][65];  // +1 pad

  const int tid = threadIdx.x;
  const float4* W14 = (const float4*)W1;
  const float4* W24 = (const float4*)W2;
  float4* w1s4 = (float4*)w1s;
  float4* w2s4 = (float4*)w2s;
#pragma unroll
  for (int t = 0; t < 4; ++t) {
    w1s4[tid + 256 * t] = W14[tid + 256 * t];
    w2s4[tid + 256 * t] = W24[tid + 256 * t];
  }
  if (tid < 64) {
    b1s[tid] = b1[tid];
    b2s[tid] = b2[tid];
  }
  __syncthreads();

  const int bh = blockIdx.x;       // 0..31
  const int s0 = blockIdx.y * 64;  // s block
  const int b = bh >> 4, h = bh & 15;
  const int j = tid & 63;
  const int rl = tid >> 6;

  for (int it = 0; it < 16; ++it) {
    __syncthreads();
    const int s = s0 + it * 4 + rl;
    xs[rl][j] = x[(((size_t)b * S_ + s) * H_ + h) * DK_ + j];
    __syncthreads();

    float a0 = 0.f, a1 = 0.f, a2 = 0.f, a3 = 0.f;
#pragma unroll
    for (int i = 0; i < 64; i += 4) {
      a0 += xs[rl][i + 0] * w1s[(i + 0) * 64 + j];
      a1 += xs[rl][i + 1] * w1s[(i + 1) * 64 + j];
      a2 += xs[rl][i + 2] * w1s[(i + 2) * 64 + j];
      a3 += xs[rl][i + 3] * w1s[(i + 3) * 64 + j];
    }
    float tm = tanhf((a0 + a1) + (a2 + a3) + b1s[j]);
    ts[rl][j] = tm;
    __syncthreads();

    float c0 = 0.f, c1 = 0.f, c2 = 0.f, c3 = 0.f;
#pragma unroll
    for (int i = 0; i < 64; i += 4) {
      c0 += ts[rl][i + 0] * w2s[(i + 0) * 64 + j];
      c1 += ts[rl][i + 1] * w2s[(i + 1) * 64 + j];
      c2 += ts[rl][i + 2] * w2s[(i + 2) * 64 + j];
      c3 += ts[rl][i + 3] * w2s[(i + 3) * 64 + j];
    }
    yt[it * 4 + rl][j] = (c0 + c1) + (c2 + c3) + b2s[j];
  }
  __syncthreads();

  // transposed write-out: thread -> (d=jj, 16 consecutive s)
  const int jj = tid >> 2, sc = tid & 3;
  union {
    unsigned short u[16];
    uint4 v[2];
  } pk;
#pragma unroll
  for (int i = 0; i < 16; ++i) pk.u[i] = f2bf(yt[sc * 16 + i][jj]);
  unsigned short* op = vt + ((size_t)bh * DK_ + jj) * S_ + s0 + sc * 16;
  *(uint4*)(op) = pk.v[0];
  *(uint4*)(op + 8) = pk.v[1];
}

// ---------------------------------------------------------------------------
// Kernel 2: MFMA flash attention (bf16 inputs, fp32 softmax/acc).
// qh,kh: bf16 [BH, S, DK]; vt: bf16 [BH, DK, S]; ctx out fp32 [B, S, H*DK].
// grid (32 bh, 32 q-blocks of 64), block 256 (4 waves x 16 q-rows).
// ---------------------------------------------------------------------------
__global__ __launch_bounds__(256, 4) void attn_kernel(
    const unsigned short* __restrict__ qhb,
    const unsigned short* __restrict__ khb,
    const unsigned short* __restrict__ vtb, float* __restrict__ ctx) {
  __shared__ __align__(16) unsigned short ks_u[64 * 64];     // [key][d], swizzled
  __shared__ __align__(16) unsigned short vs_u[64 * 64];     // [d][key], swizzled
  __shared__ __align__(16) unsigned short p_lds[4][16][72];  // per-wave P, padded

  const int tid = threadIdx.x;
  const int w = tid >> 6;
  const int l = tid & 63;
  const int lg = l >> 4;   // 4-group
  const int ll = l & 15;   // lane-in-16
  const int bh = blockIdx.x;
  const int b = bh >> 4, h = bh & 15;
  const int qblk = blockIdx.y;

  // Q fragments in registers for the whole kernel
  const int qrow = qblk * 64 + w * 16 + ll;
  const unsigned short* qp = qhb + ((size_t)bh * S_ + qrow) * DK_;
  const bf16x8 qf0 = *(const bf16x8*)(qp + lg * 8);
  const bf16x8 qf1 = *(const bf16x8*)(qp + 32 + lg * 8);

  f32x4 cacc[4];
#pragma unroll
  for (int dt = 0; dt < 4; ++dt) cacc[dt] = (f32x4){0.f, 0.f, 0.f, 0.f};
  float m_[4], l_[4];
#pragma unroll
  for (int r = 0; r < 4; ++r) {
    m_[r] = -1e30f;
    l_[r] = 0.f;
  }

  const float cs = 0.125f * 1.44269504088896340736f;  // 1/sqrt(64) * log2(e)
  unsigned short* pw = &p_lds[w][0][0];

  const int kk = tid >> 2, ch = tid & 3;  // staging roles
  const unsigned short* kgbase = khb + (size_t)bh * S_ * DK_;
  const unsigned short* vgbase = vtb + (size_t)bh * DK_ * S_;

  for (int t0 = 0; t0 < S_; t0 += 64) {
    __syncthreads();
    // ---- stage K tile [64 keys][64 d] and V^T tile [64 d][64 keys] ----
    {
      const uint4* gk = (const uint4*)(kgbase + ((size_t)(t0 + kk)) * DK_ + ch * 16);
      uint4 a0 = gk[0];
      uint4 a1 = gk[1];
      char* kd = (char*)ks_u + kk * 128;
      *(uint4*)(kd + (((ch * 2 + 0) * 16) ^ ((kk & 7) << 4))) = a0;
      *(uint4*)(kd + (((ch * 2 + 1) * 16) ^ ((kk & 7) << 4))) = a1;

      const uint4* gv = (const uint4*)(vgbase + ((size_t)kk) * S_ + t0 + ch * 16);
      uint4 b0 = gv[0];
      uint4 b1 = gv[1];
      char* vd = (char*)vs_u + kk * 128;  // kk = d row here
      *(uint4*)(vd + (((ch * 2 + 0) * 16) ^ ((kk & 7) << 4))) = b0;
      *(uint4*)(vd + (((ch * 2 + 1) * 16) ^ ((kk & 7) << 4))) = b1;
    }
    __syncthreads();

    // ---- QK^T: S[q][k] for 16 q-rows x 64 keys ----
    f32x4 sacc[4];
#pragma unroll
    for (int nt = 0; nt < 4; ++nt) {
      const int krow = nt * 16 + ll;
      const char* rowp = (const char*)ks_u + krow * 128;
      bf16x8 k0 = *(const bf16x8*)(rowp + (((lg * 8) * 2) ^ ((krow & 7) << 4)));
      bf16x8 k1 = *(const bf16x8*)(rowp + (((32 + lg * 8) * 2) ^ ((krow & 7) << 4)));
      f32x4 t = (f32x4){0.f, 0.f, 0.f, 0.f};
      t = __builtin_amdgcn_mfma_f32_16x16x32_bf16(qf0, k0, t, 0, 0, 0);
      t = __builtin_amdgcn_mfma_f32_16x16x32_bf16(qf1, k1, t, 0, 0, 0);
      sacc[nt] = t;
    }

    // ---- online softmax (fp32, exp2 domain) ----
    float sv[4][4];
#pragma unroll
    for (int nt = 0; nt < 4; ++nt)
#pragma unroll
      for (int r = 0; r < 4; ++r) sv[nt][r] = sacc[nt][r] * cs;

    float mnew[4], scl[4], psum[4];
#pragma unroll
    for (int r = 0; r < 4; ++r) {
      float t = fmaxf(fmaxf(sv[0][r], sv[1][r]), fmaxf(sv[2][r], sv[3][r]));
      t = fmaxf(t, __shfl_xor(t, 1));
      t = fmaxf(t, __shfl_xor(t, 2));
      t = fmaxf(t, __shfl_xor(t, 4));
      t = fmaxf(t, __shfl_xor(t, 8));
      mnew[r] = fmaxf(m_[r], t);
      scl[r] = exp2f(m_[r] - mnew[r]);
      m_[r] = mnew[r];
      psum[r] = 0.f;
    }

#pragma unroll
    for (int nt = 0; nt < 4; ++nt)
#pragma unroll
      for (int r = 0; r < 4; ++r) {
        float p = exp2f(sv[nt][r] - mnew[r]);
        psum[r] += p;
        pw[(lg * 4 + r) * 72 + nt * 16 + ll] = f2bf(p);
      }

#pragma unroll
    for (int r = 0; r < 4; ++r) {
      float t = psum[r];
      t += __shfl_xor(t, 1);
      t += __shfl_xor(t, 2);
      t += __shfl_xor(t, 4);
      t += __shfl_xor(t, 8);
      l_[r] = l_[r] * scl[r] + t;
    }

    // rescale running context
#pragma unroll
    for (int dt = 0; dt < 4; ++dt)
#pragma unroll
      for (int r = 0; r < 4; ++r) cacc[dt][r] *= scl[r];

    // ---- PV: ctx[q][d] += P[q][k] * V[k][d] ----
    const bf16x8 pa0 = *(const bf16x8*)((const char*)pw + ll * 144 + lg * 16);
    const bf16x8 pa1 = *(const bf16x8*)((const char*)pw + ll * 144 + 64 + lg * 16);
#pragma unroll
    for (int dt = 0; dt < 4; ++dt) {
      const int dd = dt * 16 + ll;
      const char* vrow = (const char*)vs_u + dd * 128;
      bf16x8 v0 = *(const bf16x8*)(vrow + (((lg * 8) * 2) ^ ((dd & 7) << 4)));
      bf16x8 v1 = *(const bf16x8*)(vrow + (((32 + lg * 8) * 2) ^ ((dd & 7) << 4)));
      cacc[dt] = __builtin_amdgcn_mfma_f32_16x16x32_bf16(pa0, v0, cacc[dt], 0, 0, 0);
      cacc[dt] = __builtin_amdgcn_mfma_f32_16x16x32_bf16(pa1, v1, cacc[dt], 0, 0, 0);
    }
  }

  // ---- epilogue ----
  float inv[4];
#pragma unroll
  for (int r = 0; r < 4; ++r) inv[r] = 1.0f / l_[r];
#pragma unroll
  for (int dt = 0; dt < 4; ++dt)
#pragma unroll
    for (int r = 0; r < 4; ++r) {
      const int qg = qblk * 64 + w * 16 + lg * 4 + r;
      ctx[((size_t)b * S_ + qg) * D_ + h * DK_ + dt * 16 + ll] =
          cacc[dt][r] * inv[r];
    }
}

// ---------------------------------------------------------------------------
// Kernel 3: out = ctx[4096,1024] @ Wo[1024,1024] + bo, fp32 tiled (unchanged).
// ---------------------------------------------------------------------------
__global__ __launch_bounds__(256) void out_gemm(
    const float* __restrict__ A, const float* __restrict__ Wo,
    const float* __restrict__ bo, float* __restrict__ C) {
  __shared__ float As[64][17];
  __shared__ float Bs[16][64];

  const int tid = threadIdx.x;
  const int tx = tid & 15, ty = tid >> 4;
  const int m0 = blockIdx.y * 64;
  const int n0 = blockIdx.x * 64;

  float acc[4][4];
#pragma unroll
  for (int i = 0; i < 4; ++i)
#pragma unroll
    for (int jj = 0; jj < 4; ++jj) acc[i][jj] = 0.f;

  for (int k0 = 0; k0 < D_; k0 += 16) {
    __syncthreads();
    {
      const int r = tid >> 2, kq = tid & 3;
      float4 av = *(const float4*)&A[(size_t)(m0 + r) * D_ + k0 + kq * 4];
      As[r][kq * 4 + 0] = av.x;
      As[r][kq * 4 + 1] = av.y;
      As[r][kq * 4 + 2] = av.z;
      As[r][kq * 4 + 3] = av.w;
    }
    {
      const int kk = tid >> 4, cq = tid & 15;
      *(float4*)&Bs[kk][cq * 4] =
          *(const float4*)&Wo[(size_t)(k0 + kk) * D_ + n0 + cq * 4];
    }
    __syncthreads();

#pragma unroll
    for (int kk = 0; kk < 16; ++kk) {
      float a0 = As[ty * 4 + 0][kk];
      float a1 = As[ty * 4 + 1][kk];
      float a2 = As[ty * 4 + 2][kk];
      float a3 = As[ty * 4 + 3][kk];
      float4 bq = *(const float4*)&Bs[kk][tx * 4];
      acc[0][0] += a0 * bq.x; acc[0][1] += a0 * bq.y;
      acc[0][2] += a0 * bq.z; acc[0][3] += a0 * bq.w;
      acc[1][0] += a1 * bq.x; acc[1][1] += a1 * bq.y;
      acc[1][2] += a1 * bq.z; acc[1][3] += a1 * bq.w;
      acc[2][0] += a2 * bq.x; acc[2][1] += a2 * bq.y;
      acc[2][2] += a2 * bq.z; acc[2][3] += a2 * bq.w;
      acc[3][0] += a3 * bq.x; acc[3][1] += a3 * bq.y;
      acc[3][2] += a3 * bq.z; acc[3][3] += a3 * bq.w;
    }
  }

  const float4 bov = *(const float4*)&bo[n0 + tx * 4];
#pragma unroll
  for (int i = 0; i < 4; ++i) {
    float4 o;
    o.x = acc[i][0] + bov.x;
    o.y = acc[i][1] + bov.y;
    o.z = acc[i][2] + bov.z;
    o.w = acc[i][3] + bov.w;
    *(float4*)&C[(size_t)(m0 + ty * 4 + i) * D_ + n0 + tx * 4] = o;
  }
}

// ---------------------------------------------------------------------------
extern "C" void kernel_launch(void* const* d_in, const int* in_sizes, int n_in,
                              void* d_out, int out_size, void* d_ws,
                              size_t ws_size, hipStream_t stream) {
  const float* q = (const float*)d_in[0];
  const float* k = (const float*)d_in[1];
  const float* v = (const float*)d_in[2];
  const float* Wq1 = (const float*)d_in[3];
  const float* bq1 = (const float*)d_in[4];
  const float* Wq2 = (const float*)d_in[5];
  const float* bq2 = (const float*)d_in[6];
  const float* Wk1 = (const float*)d_in[7];
  const float* bk1 = (const float*)d_in[8];
  const float* Wk2 = (const float*)d_in[9];
  const float* bk2 = (const float*)d_in[10];
  const float* Wv1 = (const float*)d_in[11];
  const float* bv1 = (const float*)d_in[12];
  const float* Wv2 = (const float*)d_in[13];
  const float* bv2 = (const float*)d_in[14];
  const float* Wo = (const float*)d_in[15];
  const float* bo = (const float*)d_in[16];
  float* out = (float*)d_out;

  const size_t TEN = (size_t)B_ * H_ * S_ * DK_;  // 4,194,304 elements
  char* ws = (char*)d_ws;
  unsigned short* qhb = (unsigned short*)ws;                  // bf16 [BH,S,DK]
  unsigned short* khb = (unsigned short*)(ws + TEN * 2);      // bf16 [BH,S,DK]
  unsigned short* vtb = (unsigned short*)(ws + TEN * 4);      // bf16 [BH,DK,S]
  float* ctx = (float*)(ws + TEN * 6);                        // fp32 [B,S,D]

  quantum_kernel<<<dim3(2048), 256, 0, stream>>>(q, Wq1, bq1, Wq2, bq2, qhb);
  quantum_kernel<<<dim3(2048), 256, 0, stream>>>(k, Wk1, bk1, Wk2, bk2, khb);
  quantum_v_kernel<<<dim3(32, 32), 256, 0, stream>>>(v, Wv1, bv1, Wv2, bv2, vtb);

  attn_kernel<<<dim3(32, 32), 256, 0, stream>>>(qhb, khb, vtb, ctx);

  out_gemm<<<dim3(16, 64), 256, 0, stream>>>(ctx, Wo, bo, out);
}

// Round 3
// 337.346 us; speedup vs baseline: 4.3414x; 1.2936x over previous
//
#include <hip/hip_runtime.h>

#define B_ 2
#define S_ 2048
#define D_ 1024
#define H_ 16
#define DK_ 64

typedef float f32x4 __attribute__((ext_vector_type(4)));
typedef short bf16x8 __attribute__((ext_vector_type(8)));

static __device__ __forceinline__ unsigned short f2bf(float f) {
  unsigned u = __float_as_uint(f);
  unsigned r = (u + 0x7FFFu + ((u >> 16) & 1u)) >> 16;
  return (unsigned short)r;
}

static __device__ __forceinline__ void load16_lds(const void* g, void* lds) {
  __builtin_amdgcn_global_load_lds(
      (const __attribute__((address_space(1))) unsigned int*)g,
      (__attribute__((address_space(3))) unsigned int*)lds, 16, 0, 0);
}

// ---------------------------------------------------------------------------
// Kernel 1a: quantum transform for q,k.  out bf16 [B, H, S, DK].
// ---------------------------------------------------------------------------
__global__ __launch_bounds__(256) void quantum_kernel(
    const float* __restrict__ x,
    const float* __restrict__ W1, const float* __restrict__ b1,
    const float* __restrict__ W2, const float* __restrict__ b2,
    unsigned short* __restrict__ out) {
  __shared__ float w1s[64 * 64];
  __shared__ float w2s[64 * 64];
  __shared__ float b1s[64], b2s[64];
  __shared__ float xs[4][64];
  __shared__ float ts[4][64];

  const int tid = threadIdx.x;
  const float4* W14 = (const float4*)W1;
  const float4* W24 = (const float4*)W2;
  float4* w1s4 = (float4*)w1s;
  float4* w2s4 = (float4*)w2s;
#pragma unroll
  for (int t = 0; t < 4; ++t) {
    w1s4[tid + 256 * t] = W14[tid + 256 * t];
    w2s4[tid + 256 * t] = W24[tid + 256 * t];
  }
  if (tid < 64) {
    b1s[tid] = b1[tid];
    b2s[tid] = b2[tid];
  }
  __syncthreads();

  const int j = tid & 63;
  const int rl = tid >> 6;
  const int ngroups = (B_ * S_ * H_) / 4;
  float* xs_flat = &xs[0][0];

  for (int g = blockIdx.x; g < ngroups; g += gridDim.x) {
    const int r0 = g * 4;
    xs_flat[tid] = x[(size_t)r0 * 64 + tid];
    __syncthreads();

    float a0 = 0.f, a1 = 0.f, a2 = 0.f, a3 = 0.f;
#pragma unroll
    for (int i = 0; i < 64; i += 4) {
      a0 += xs[rl][i + 0] * w1s[(i + 0) * 64 + j];
      a1 += xs[rl][i + 1] * w1s[(i + 1) * 64 + j];
      a2 += xs[rl][i + 2] * w1s[(i + 2) * 64 + j];
      a3 += xs[rl][i + 3] * w1s[(i + 3) * 64 + j];
    }
    float tm = tanhf((a0 + a1) + (a2 + a3) + b1s[j]);
    ts[rl][j] = tm;
    __syncthreads();

    float c0 = 0.f, c1 = 0.f, c2 = 0.f, c3 = 0.f;
#pragma unroll
    for (int i = 0; i < 64; i += 4) {
      c0 += ts[rl][i + 0] * w2s[(i + 0) * 64 + j];
      c1 += ts[rl][i + 1] * w2s[(i + 1) * 64 + j];
      c2 += ts[rl][i + 2] * w2s[(i + 2) * 64 + j];
      c3 += ts[rl][i + 3] * w2s[(i + 3) * 64 + j];
    }
    float y = (c0 + c1) + (c2 + c3) + b2s[j];

    const int row = r0 + rl;
    const int b = row >> 15;
    const int rem = row & 32767;
    const int s = rem >> 4;
    const int h = rem & 15;
    out[(((size_t)b * H_ + h) * S_ + s) * DK_ + j] = f2bf(y);
  }
}

// ---------------------------------------------------------------------------
// Kernel 1b: quantum transform for v, output TRANSPOSED bf16 [B, H, DK, S].
// ---------------------------------------------------------------------------
__global__ __launch_bounds__(256) void quantum_v_kernel(
    const float* __restrict__ x,
    const float* __restrict__ W1, const float* __restrict__ b1,
    const float* __restrict__ W2, const float* __restrict__ b2,
    unsigned short* __restrict__ vt) {
  __shared__ float w1s[64 * 64];
  __shared__ float w2s[64 * 64];
  __shared__ float b1s[64], b2s[64];
  __shared__ float xs[4][64];
  __shared__ float ts[4][64];
  __shared__ float yt[64][65];  // +1 pad

  const int tid = threadIdx.x;
  const float4* W14 = (const float4*)W1;
  const float4* W24 = (const float4*)W2;
  float4* w1s4 = (float4*)w1s;
  float4* w2s4 = (float4*)w2s;
#pragma unroll
  for (int t = 0; t < 4; ++t) {
    w1s4[tid + 256 * t] = W14[tid + 256 * t];
    w2s4[tid + 256 * t] = W24[tid + 256 * t];
  }
  if (tid < 64) {
    b1s[tid] = b1[tid];
    b2s[tid] = b2[tid];
  }
  __syncthreads();

  const int bh = blockIdx.x;
  const int s0 = blockIdx.y * 64;
  const int b = bh >> 4, h = bh & 15;
  const int j = tid & 63;
  const int rl = tid >> 6;

  for (int it = 0; it < 16; ++it) {
    __syncthreads();
    const int s = s0 + it * 4 + rl;
    xs[rl][j] = x[(((size_t)b * S_ + s) * H_ + h) * DK_ + j];
    __syncthreads();

    float a0 = 0.f, a1 = 0.f, a2 = 0.f, a3 = 0.f;
#pragma unroll
    for (int i = 0; i < 64; i += 4) {
      a0 += xs[rl][i + 0] * w1s[(i + 0) * 64 + j];
      a1 += xs[rl][i + 1] * w1s[(i + 1) * 64 + j];
      a2 += xs[rl][i + 2] * w1s[(i + 2) * 64 + j];
      a3 += xs[rl][i + 3] * w1s[(i + 3) * 64 + j];
    }
    float tm = tanhf((a0 + a1) + (a2 + a3) + b1s[j]);
    ts[rl][j] = tm;
    __syncthreads();

    float c0 = 0.f, c1 = 0.f, c2 = 0.f, c3 = 0.f;
#pragma unroll
    for (int i = 0; i < 64; i += 4) {
      c0 += ts[rl][i + 0] * w2s[(i + 0) * 64 + j];
      c1 += ts[rl][i + 1] * w2s[(i + 1) * 64 + j];
      c2 += ts[rl][i + 2] * w2s[(i + 2) * 64 + j];
      c3 += ts[rl][i + 3] * w2s[(i + 3) * 64 + j];
    }
    yt[it * 4 + rl][j] = (c0 + c1) + (c2 + c3) + b2s[j];
  }
  __syncthreads();

  const int jj = tid >> 2, sc = tid & 3;
  union {
    unsigned short u[16];
    uint4 v[2];
  } pk;
#pragma unroll
  for (int i = 0; i < 16; ++i) pk.u[i] = f2bf(yt[sc * 16 + i][jj]);
  unsigned short* op = vt + ((size_t)bh * DK_ + jj) * S_ + s0 + sc * 16;
  *(uint4*)(op) = pk.v[0];
  *(uint4*)(op + 8) = pk.v[1];
}

// ---------------------------------------------------------------------------
// Kernel 2: MFMA flash attention (bf16 in, fp32 softmax/acc, bf16 ctx out).
// ---------------------------------------------------------------------------
__global__ __launch_bounds__(256, 4) void attn_kernel(
    const unsigned short* __restrict__ qhb,
    const unsigned short* __restrict__ khb,
    const unsigned short* __restrict__ vtb,
    unsigned short* __restrict__ ctxb) {
  __shared__ __align__(16) unsigned short ks_u[64 * 64];
  __shared__ __align__(16) unsigned short vs_u[64 * 64];
  __shared__ __align__(16) unsigned short p_lds[4][16][72];

  const int tid = threadIdx.x;
  const int w = tid >> 6;
  const int l = tid & 63;
  const int lg = l >> 4;
  const int ll = l & 15;
  const int bh = blockIdx.x;
  const int b = bh >> 4, h = bh & 15;
  const int qblk = blockIdx.y;

  const int qrow = qblk * 64 + w * 16 + ll;
  const unsigned short* qp = qhb + ((size_t)bh * S_ + qrow) * DK_;
  const bf16x8 qf0 = *(const bf16x8*)(qp + lg * 8);
  const bf16x8 qf1 = *(const bf16x8*)(qp + 32 + lg * 8);

  f32x4 cacc[4];
#pragma unroll
  for (int dt = 0; dt < 4; ++dt) cacc[dt] = (f32x4){0.f, 0.f, 0.f, 0.f};
  float m_[4], l_[4];
#pragma unroll
  for (int r = 0; r < 4; ++r) {
    m_[r] = -1e30f;
    l_[r] = 0.f;
  }

  const float cs = 0.125f * 1.44269504088896340736f;
  unsigned short* pw = &p_lds[w][0][0];

  const int kk = tid >> 2, ch = tid & 3;
  const unsigned short* kgbase = khb + (size_t)bh * S_ * DK_;
  const unsigned short* vgbase = vtb + (size_t)bh * DK_ * S_;

  for (int t0 = 0; t0 < S_; t0 += 64) {
    __syncthreads();
    {
      const uint4* gk = (const uint4*)(kgbase + ((size_t)(t0 + kk)) * DK_ + ch * 16);
      uint4 a0 = gk[0];
      uint4 a1 = gk[1];
      char* kd = (char*)ks_u + kk * 128;
      *(uint4*)(kd + (((ch * 2 + 0) * 16) ^ ((kk & 7) << 4))) = a0;
      *(uint4*)(kd + (((ch * 2 + 1) * 16) ^ ((kk & 7) << 4))) = a1;

      const uint4* gv = (const uint4*)(vgbase + ((size_t)kk) * S_ + t0 + ch * 16);
      uint4 b0 = gv[0];
      uint4 b1 = gv[1];
      char* vd = (char*)vs_u + kk * 128;
      *(uint4*)(vd + (((ch * 2 + 0) * 16) ^ ((kk & 7) << 4))) = b0;
      *(uint4*)(vd + (((ch * 2 + 1) * 16) ^ ((kk & 7) << 4))) = b1;
    }
    __syncthreads();

    f32x4 sacc[4];
#pragma unroll
    for (int nt = 0; nt < 4; ++nt) {
      const int krow = nt * 16 + ll;
      const char* rowp = (const char*)ks_u + krow * 128;
      bf16x8 k0 = *(const bf16x8*)(rowp + (((lg * 8) * 2) ^ ((krow & 7) << 4)));
      bf16x8 k1 = *(const bf16x8*)(rowp + (((32 + lg * 8) * 2) ^ ((krow & 7) << 4)));
      f32x4 t = (f32x4){0.f, 0.f, 0.f, 0.f};
      t = __builtin_amdgcn_mfma_f32_16x16x32_bf16(qf0, k0, t, 0, 0, 0);
      t = __builtin_amdgcn_mfma_f32_16x16x32_bf16(qf1, k1, t, 0, 0, 0);
      sacc[nt] = t;
    }

    float sv[4][4];
#pragma unroll
    for (int nt = 0; nt < 4; ++nt)
#pragma unroll
      for (int r = 0; r < 4; ++r) sv[nt][r] = sacc[nt][r] * cs;

    float mnew[4], scl[4], psum[4];
#pragma unroll
    for (int r = 0; r < 4; ++r) {
      float t = fmaxf(fmaxf(sv[0][r], sv[1][r]), fmaxf(sv[2][r], sv[3][r]));
      t = fmaxf(t, __shfl_xor(t, 1));
      t = fmaxf(t, __shfl_xor(t, 2));
      t = fmaxf(t, __shfl_xor(t, 4));
      t = fmaxf(t, __shfl_xor(t, 8));
      mnew[r] = fmaxf(m_[r], t);
      scl[r] = exp2f(m_[r] - mnew[r]);
      m_[r] = mnew[r];
      psum[r] = 0.f;
    }

#pragma unroll
    for (int nt = 0; nt < 4; ++nt)
#pragma unroll
      for (int r = 0; r < 4; ++r) {
        float p = exp2f(sv[nt][r] - mnew[r]);
        psum[r] += p;
        pw[(lg * 4 + r) * 72 + nt * 16 + ll] = f2bf(p);
      }

#pragma unroll
    for (int r = 0; r < 4; ++r) {
      float t = psum[r];
      t += __shfl_xor(t, 1);
      t += __shfl_xor(t, 2);
      t += __shfl_xor(t, 4);
      t += __shfl_xor(t, 8);
      l_[r] = l_[r] * scl[r] + t;
    }

#pragma unroll
    for (int dt = 0; dt < 4; ++dt)
#pragma unroll
      for (int r = 0; r < 4; ++r) cacc[dt][r] *= scl[r];

    const bf16x8 pa0 = *(const bf16x8*)((const char*)pw + ll * 144 + lg * 16);
    const bf16x8 pa1 = *(const bf16x8*)((const char*)pw + ll * 144 + 64 + lg * 16);
#pragma unroll
    for (int dt = 0; dt < 4; ++dt) {
      const int dd = dt * 16 + ll;
      const char* vrow = (const char*)vs_u + dd * 128;
      bf16x8 v0 = *(const bf16x8*)(vrow + (((lg * 8) * 2) ^ ((dd & 7) << 4)));
      bf16x8 v1 = *(const bf16x8*)(vrow + (((32 + lg * 8) * 2) ^ ((dd & 7) << 4)));
      cacc[dt] = __builtin_amdgcn_mfma_f32_16x16x32_bf16(pa0, v0, cacc[dt], 0, 0, 0);
      cacc[dt] = __builtin_amdgcn_mfma_f32_16x16x32_bf16(pa1, v1, cacc[dt], 0, 0, 0);
    }
  }

  float inv[4];
#pragma unroll
  for (int r = 0; r < 4; ++r) inv[r] = 1.0f / l_[r];
#pragma unroll
  for (int dt = 0; dt < 4; ++dt)
#pragma unroll
    for (int r = 0; r < 4; ++r) {
      const int qg = qblk * 64 + w * 16 + lg * 4 + r;
      ctxb[((size_t)b * S_ + qg) * D_ + h * DK_ + dt * 16 + ll] =
          f2bf(cacc[dt][r] * inv[r]);
    }
}

// ---------------------------------------------------------------------------
// Kernel 3a: Wo fp32 [K][N] -> WoT bf16 [N][K]
// ---------------------------------------------------------------------------
__global__ __launch_bounds__(256) void wo_transpose(
    const float* __restrict__ Wo, unsigned short* __restrict__ WoT) {
  __shared__ float t[64][65];
  const int k0 = blockIdx.x * 64, n0 = blockIdx.y * 64;
  const int r = threadIdx.x >> 4, c4 = threadIdx.x & 15;
#pragma unroll
  for (int i = 0; i < 4; ++i) {
    float4 v = *(const float4*)&Wo[(size_t)(k0 + r + 16 * i) * D_ + n0 + c4 * 4];
    t[r + 16 * i][c4 * 4 + 0] = v.x;
    t[r + 16 * i][c4 * 4 + 1] = v.y;
    t[r + 16 * i][c4 * 4 + 2] = v.z;
    t[r + 16 * i][c4 * 4 + 3] = v.w;
  }
  __syncthreads();
  const int n = threadIdx.x >> 2, kc = threadIdx.x & 3;
  union {
    unsigned short u[16];
    uint4 v[2];
  } pk;
#pragma unroll
  for (int j = 0; j < 16; ++j) pk.u[j] = f2bf(t[kc * 16 + j][n]);
  unsigned short* op = WoT + (size_t)(n0 + n) * D_ + k0 + kc * 16;
  *(uint4*)op = pk.v[0];
  *(uint4*)(op + 8) = pk.v[1];
}

// ---------------------------------------------------------------------------
// Kernel 3b: out[4096,1024] = ctx_bf16 @ WoT^T + bo, bf16 MFMA, fp32 out.
// 128x128 tile, BK=64, 4 waves (2x2). Swizzled LDS via pre-swizzled source.
// ---------------------------------------------------------------------------
__global__ __launch_bounds__(256) void out_gemm_mfma(
    const unsigned short* __restrict__ A,   // [4096][1024] bf16
    const unsigned short* __restrict__ BT,  // [1024][1024] bf16 = Wo^T
    const float* __restrict__ bo, float* __restrict__ C) {
  __shared__ __align__(16) unsigned short As[128 * 64];  // 16KB
  __shared__ __align__(16) unsigned short Bs[128 * 64];  // 16KB

  const int tid = threadIdx.x;
  const int w = tid >> 6, l = tid & 63;
  const int ll = l & 15, lg = l >> 4;
  const int wr = w >> 1, wc = w & 1;
  const int m0 = blockIdx.y * 128, n0 = blockIdx.x * 128;

  // staging: LDS linear offset o holds G[row=o/128][slot = (o%128/16) ^ (row&7)]
  const int srow = l >> 3;                 // 0..7 within 8-row chunk
  const int sslot = (l & 7) ^ srow;        // inverse swizzle on source
  const int g_off = sslot * 8;             // bf16 elems within K-slice

  f32x4 acc[4][4];
#pragma unroll
  for (int mt = 0; mt < 4; ++mt)
#pragma unroll
    for (int nt = 0; nt < 4; ++nt) acc[mt][nt] = (f32x4){0.f, 0.f, 0.f, 0.f};

  for (int k0 = 0; k0 < D_; k0 += 64) {
    __syncthreads();
#pragma unroll
    for (int c = 0; c < 4; ++c) {
      const int row = c * 32 + w * 8 + srow;
      load16_lds(A + (size_t)(m0 + row) * D_ + k0 + g_off,
                 (char*)As + c * 4096 + w * 1024);
      load16_lds(BT + (size_t)(n0 + row) * D_ + k0 + g_off,
                 (char*)Bs + c * 4096 + w * 1024);
    }
    __syncthreads();

#pragma unroll
    for (int half = 0; half < 2; ++half) {
      bf16x8 af[4], bfr[4];
#pragma unroll
      for (int mt = 0; mt < 4; ++mt) {
        const int row = wr * 64 + mt * 16 + ll;
        af[mt] = *(const bf16x8*)((const char*)As + row * 128 +
                                  (((half * 4 + lg) ^ (row & 7)) << 4));
      }
#pragma unroll
      for (int nt = 0; nt < 4; ++nt) {
        const int rowb = wc * 64 + nt * 16 + ll;
        bfr[nt] = *(const bf16x8*)((const char*)Bs + rowb * 128 +
                                   (((half * 4 + lg) ^ (rowb & 7)) << 4));
      }
#pragma unroll
      for (int mt = 0; mt < 4; ++mt)
#pragma unroll
        for (int nt = 0; nt < 4; ++nt)
          acc[mt][nt] = __builtin_amdgcn_mfma_f32_16x16x32_bf16(
              af[mt], bfr[nt], acc[mt][nt], 0, 0, 0);
    }
  }

  // epilogue: C[m][n] = acc + bo[n]
#pragma unroll
  for (int nt = 0; nt < 4; ++nt) {
    const int col = n0 + wc * 64 + nt * 16 + ll;
    const float bv = bo[col];
#pragma unroll
    for (int mt = 0; mt < 4; ++mt) {
      const int row0 = m0 + wr * 64 + mt * 16 + lg * 4;
#pragma unroll
      for (int r = 0; r < 4; ++r)
        C[(size_t)(row0 + r) * D_ + col] = acc[mt][nt][r] + bv;
    }
  }
}

// ---------------------------------------------------------------------------
extern "C" void kernel_launch(void* const* d_in, const int* in_sizes, int n_in,
                              void* d_out, int out_size, void* d_ws,
                              size_t ws_size, hipStream_t stream) {
  const float* q = (const float*)d_in[0];
  const float* k = (const float*)d_in[1];
  const float* v = (const float*)d_in[2];
  const float* Wq1 = (const float*)d_in[3];
  const float* bq1 = (const float*)d_in[4];
  const float* Wq2 = (const float*)d_in[5];
  const float* bq2 = (const float*)d_in[6];
  const float* Wk1 = (const float*)d_in[7];
  const float* bk1 = (const float*)d_in[8];
  const float* Wk2 = (const float*)d_in[9];
  const float* bk2 = (const float*)d_in[10];
  const float* Wv1 = (const float*)d_in[11];
  const float* bv1 = (const float*)d_in[12];
  const float* Wv2 = (const float*)d_in[13];
  const float* bv2 = (const float*)d_in[14];
  const float* Wo = (const float*)d_in[15];
  const float* bo = (const float*)d_in[16];
  float* out = (float*)d_out;

  const size_t TEN = (size_t)B_ * H_ * S_ * DK_;  // 4,194,304 elements
  char* ws = (char*)d_ws;
  unsigned short* qhb = (unsigned short*)ws;              // bf16 [BH,S,DK]
  unsigned short* khb = (unsigned short*)(ws + TEN * 2);  // bf16 [BH,S,DK]
  unsigned short* vtb = (unsigned short*)(ws + TEN * 4);  // bf16 [BH,DK,S]
  unsigned short* ctxb = (unsigned short*)(ws + TEN * 6); // bf16 [B,S,D]
  unsigned short* wot = (unsigned short*)(ws + TEN * 8);  // bf16 [N,K] = Wo^T

  quantum_kernel<<<dim3(2048), 256, 0, stream>>>(q, Wq1, bq1, Wq2, bq2, qhb);
  quantum_kernel<<<dim3(2048), 256, 0, stream>>>(k, Wk1, bk1, Wk2, bk2, khb);
  quantum_v_kernel<<<dim3(32, 32), 256, 0, stream>>>(v, Wv1, bv1, Wv2, bv2, vtb);
  wo_transpose<<<dim3(16, 16), 256, 0, stream>>>(Wo, wot);

  attn_kernel<<<dim3(32, 32), 256, 0, stream>>>(qhb, khb, vtb, ctxb);

  out_gemm_mfma<<<dim3(8, 32), 256, 0, stream>>>(ctxb, wot, bo, out);
}

// Round 4
// 287.456 us; speedup vs baseline: 5.0949x; 1.1736x over previous
//
#include <hip/hip_runtime.h>

#define B_ 2
#define S_ 2048
#define D_ 1024
#define H_ 16
#define DK_ 64

typedef float f32x4 __attribute__((ext_vector_type(4)));
typedef float f32x16 __attribute__((ext_vector_type(16)));
typedef short bf16x8 __attribute__((ext_vector_type(8)));

static __device__ __forceinline__ unsigned short f2bf(float f) {
  unsigned u = __float_as_uint(f);
  unsigned r = (u + 0x7FFFu + ((u >> 16) & 1u)) >> 16;
  return (unsigned short)r;
}

static __device__ __forceinline__ unsigned cvtpk_bf16(float lo, float hi) {
  unsigned r;
  asm("v_cvt_pk_bf16_f32 %0, %1, %2" : "=v"(r) : "v"(lo), "v"(hi));
  return r;
}

static __device__ __forceinline__ void load16_lds(const void* g, void* lds) {
  __builtin_amdgcn_global_load_lds(
      (const __attribute__((address_space(1))) unsigned int*)g,
      (__attribute__((address_space(3))) unsigned int*)lds, 16, 0, 0);
}

// ---------------------------------------------------------------------------
// Kernel 1a: quantum transform for q,k.  out bf16 [B, H, S, DK], y *= scale.
// ---------------------------------------------------------------------------
__global__ __launch_bounds__(256) void quantum_kernel(
    const float* __restrict__ x,
    const float* __restrict__ W1, const float* __restrict__ b1,
    const float* __restrict__ W2, const float* __restrict__ b2,
    unsigned short* __restrict__ out, float scale) {
  __shared__ float w1s[64 * 64];
  __shared__ float w2s[64 * 64];
  __shared__ float b1s[64], b2s[64];
  __shared__ float xs[4][64];
  __shared__ float ts[4][64];

  const int tid = threadIdx.x;
  const float4* W14 = (const float4*)W1;
  const float4* W24 = (const float4*)W2;
  float4* w1s4 = (float4*)w1s;
  float4* w2s4 = (float4*)w2s;
#pragma unroll
  for (int t = 0; t < 4; ++t) {
    w1s4[tid + 256 * t] = W14[tid + 256 * t];
    w2s4[tid + 256 * t] = W24[tid + 256 * t];
  }
  if (tid < 64) {
    b1s[tid] = b1[tid];
    b2s[tid] = b2[tid];
  }
  __syncthreads();

  const int j = tid & 63;
  const int rl = tid >> 6;
  const int ngroups = (B_ * S_ * H_) / 4;
  float* xs_flat = &xs[0][0];

  for (int g = blockIdx.x; g < ngroups; g += gridDim.x) {
    const int r0 = g * 4;
    xs_flat[tid] = x[(size_t)r0 * 64 + tid];
    __syncthreads();

    float a0 = 0.f, a1 = 0.f, a2 = 0.f, a3 = 0.f;
#pragma unroll
    for (int i = 0; i < 64; i += 4) {
      a0 += xs[rl][i + 0] * w1s[(i + 0) * 64 + j];
      a1 += xs[rl][i + 1] * w1s[(i + 1) * 64 + j];
      a2 += xs[rl][i + 2] * w1s[(i + 2) * 64 + j];
      a3 += xs[rl][i + 3] * w1s[(i + 3) * 64 + j];
    }
    float tm = tanhf((a0 + a1) + (a2 + a3) + b1s[j]);
    ts[rl][j] = tm;
    __syncthreads();

    float c0 = 0.f, c1 = 0.f, c2 = 0.f, c3 = 0.f;
#pragma unroll
    for (int i = 0; i < 64; i += 4) {
      c0 += ts[rl][i + 0] * w2s[(i + 0) * 64 + j];
      c1 += ts[rl][i + 1] * w2s[(i + 1) * 64 + j];
      c2 += ts[rl][i + 2] * w2s[(i + 2) * 64 + j];
      c3 += ts[rl][i + 3] * w2s[(i + 3) * 64 + j];
    }
    float y = ((c0 + c1) + (c2 + c3) + b2s[j]) * scale;

    const int row = r0 + rl;
    const int b = row >> 15;
    const int rem = row & 32767;
    const int s = rem >> 4;
    const int h = rem & 15;
    out[(((size_t)b * H_ + h) * S_ + s) * DK_ + j] = f2bf(y);
  }
}

// ---------------------------------------------------------------------------
// Kernel 1b: quantum transform for v, output TRANSPOSED bf16 [B, H, DK, S].
// ---------------------------------------------------------------------------
__global__ __launch_bounds__(256) void quantum_v_kernel(
    const float* __restrict__ x,
    const float* __restrict__ W1, const float* __restrict__ b1,
    const float* __restrict__ W2, const float* __restrict__ b2,
    unsigned short* __restrict__ vt) {
  __shared__ float w1s[64 * 64];
  __shared__ float w2s[64 * 64];
  __shared__ float b1s[64], b2s[64];
  __shared__ float xs[4][64];
  __shared__ float ts[4][64];
  __shared__ float yt[64][65];  // +1 pad

  const int tid = threadIdx.x;
  const float4* W14 = (const float4*)W1;
  const float4* W24 = (const float4*)W2;
  float4* w1s4 = (float4*)w1s;
  float4* w2s4 = (float4*)w2s;
#pragma unroll
  for (int t = 0; t < 4; ++t) {
    w1s4[tid + 256 * t] = W14[tid + 256 * t];
    w2s4[tid + 256 * t] = W24[tid + 256 * t];
  }
  if (tid < 64) {
    b1s[tid] = b1[tid];
    b2s[tid] = b2[tid];
  }
  __syncthreads();

  const int bh = blockIdx.x;
  const int s0 = blockIdx.y * 64;
  const int b = bh >> 4, h = bh & 15;
  const int j = tid & 63;
  const int rl = tid >> 6;

  for (int it = 0; it < 16; ++it) {
    __syncthreads();
    const int s = s0 + it * 4 + rl;
    xs[rl][j] = x[(((size_t)b * S_ + s) * H_ + h) * DK_ + j];
    __syncthreads();

    float a0 = 0.f, a1 = 0.f, a2 = 0.f, a3 = 0.f;
#pragma unroll
    for (int i = 0; i < 64; i += 4) {
      a0 += xs[rl][i + 0] * w1s[(i + 0) * 64 + j];
      a1 += xs[rl][i + 1] * w1s[(i + 1) * 64 + j];
      a2 += xs[rl][i + 2] * w1s[(i + 2) * 64 + j];
      a3 += xs[rl][i + 3] * w1s[(i + 3) * 64 + j];
    }
    float tm = tanhf((a0 + a1) + (a2 + a3) + b1s[j]);
    ts[rl][j] = tm;
    __syncthreads();

    float c0 = 0.f, c1 = 0.f, c2 = 0.f, c3 = 0.f;
#pragma unroll
    for (int i = 0; i < 64; i += 4) {
      c0 += ts[rl][i + 0] * w2s[(i + 0) * 64 + j];
      c1 += ts[rl][i + 1] * w2s[(i + 1) * 64 + j];
      c2 += ts[rl][i + 2] * w2s[(i + 2) * 64 + j];
      c3 += ts[rl][i + 3] * w2s[(i + 3) * 64 + j];
    }
    yt[it * 4 + rl][j] = (c0 + c1) + (c2 + c3) + b2s[j];
  }
  __syncthreads();

  const int jj = tid >> 2, sc = tid & 3;
  union {
    unsigned short u[16];
    uint4 v[2];
  } pk;
#pragma unroll
  for (int i = 0; i < 16; ++i) pk.u[i] = f2bf(yt[sc * 16 + i][jj]);
  unsigned short* op = vt + ((size_t)bh * DK_ + jj) * S_ + s0 + sc * 16;
  *(uint4*)(op) = pk.v[0];
  *(uint4*)(op + 8) = pk.v[1];
}

// ---------------------------------------------------------------------------
// Kernel 2: MFMA flash attention, swapped-QK^T 32x32x16 structure.
// qh (pre-scaled by 1/8*log2e), kh: bf16 [BH,S,DK]; vt: bf16 [BH,DK,S].
// S^T = mfma(K, Q): lane owns q = l&31 -> lane-local softmax (defer-max).
// P -> A-frag via cvt_pk + xor32 exchange; O[q][d] = mfma(P, V^T-tile).
// grid (32 bh, 16 q-blocks of 128), 4 waves x 32 q.
// ---------------------------------------------------------------------------
__global__ __launch_bounds__(256, 2) void attn_kernel(
    const unsigned short* __restrict__ qhb,
    const unsigned short* __restrict__ khb,
    const unsigned short* __restrict__ vtb,
    unsigned short* __restrict__ ctxb) {
  __shared__ __align__(16) unsigned short ks_u[64 * 64];  // [key][d] swizzled
  __shared__ __align__(16) unsigned short vs_u[64 * 64];  // [d][key] swizzled

  const int tid = threadIdx.x;
  const int w = tid >> 6;
  const int l = tid & 63;
  const int lq = l & 31;  // q-col in QK^T, d-col in PV
  const int hi = l >> 5;
  const int bh = blockIdx.x;
  const int b = bh >> 4, h = bh & 15;
  const int q0 = blockIdx.y * 128 + w * 32;

  // Q fragments (B-operand): Q[q0+lq][kc*16 + hi*8 + j], j contiguous
  const unsigned short* qp = qhb + ((size_t)bh * S_ + q0 + lq) * DK_ + hi * 8;
  bf16x8 qf[4];
#pragma unroll
  for (int kc = 0; kc < 4; ++kc) qf[kc] = *(const bf16x8*)(qp + kc * 16);

  f32x16 o0 = {}, o1 = {};  // O[q=crow(r,hi)][d = dt*32 + lq]
  float m_ = -1e30f, l_ = 0.f;

  const int kk = tid >> 2, ch = tid & 3;  // staging roles
  const unsigned short* kgbase = khb + (size_t)bh * S_ * DK_;
  const unsigned short* vgbase = vtb + (size_t)bh * DK_ * S_;

  for (int t0 = 0; t0 < S_; t0 += 64) {
    __syncthreads();
    {  // stage K [64 key][64 d] and V^T [64 d][64 key], XOR-swizzled rows
      const uint4* gk = (const uint4*)(kgbase + ((size_t)(t0 + kk)) * DK_ + ch * 16);
      uint4 a0 = gk[0];
      uint4 a1 = gk[1];
      char* kd = (char*)ks_u + kk * 128;
      *(uint4*)(kd + (((ch * 2 + 0) ^ (kk & 7)) << 4)) = a0;
      *(uint4*)(kd + (((ch * 2 + 1) ^ (kk & 7)) << 4)) = a1;

      const uint4* gv = (const uint4*)(vgbase + ((size_t)kk) * S_ + t0 + ch * 16);
      uint4 b0 = gv[0];
      uint4 b1 = gv[1];
      char* vd = (char*)vs_u + kk * 128;
      *(uint4*)(vd + (((ch * 2 + 0) ^ (kk & 7)) << 4)) = b0;
      *(uint4*)(vd + (((ch * 2 + 1) ^ (kk & 7)) << 4)) = b1;
    }
    __syncthreads();

    // ---- QK^T: S^T[k = kt*32 + crow(r,hi)][q = lq], log2-domain ----
    f32x16 s0 = {}, s1 = {};
#pragma unroll
    for (int kc = 0; kc < 4; ++kc) {
      const int slot = kc * 2 + hi;
      bf16x8 k0 = *(const bf16x8*)((const char*)ks_u + lq * 128 +
                                   ((slot ^ (lq & 7)) << 4));
      bf16x8 k1 = *(const bf16x8*)((const char*)ks_u + (32 + lq) * 128 +
                                   ((slot ^ (lq & 7)) << 4));
      s0 = __builtin_amdgcn_mfma_f32_32x32x16_bf16(k0, qf[kc], s0, 0, 0, 0);
      s1 = __builtin_amdgcn_mfma_f32_32x32x16_bf16(k1, qf[kc], s1, 0, 0, 0);
    }

    // ---- lane-local online softmax with defer-max (THR=8) ----
    float pmax = s0[0];
#pragma unroll
    for (int i = 1; i < 16; ++i) pmax = fmaxf(pmax, s0[i]);
#pragma unroll
    for (int i = 0; i < 16; ++i) pmax = fmaxf(pmax, s1[i]);
    pmax = fmaxf(pmax, __shfl_xor(pmax, 32));

    if (!__all(pmax <= m_ + 8.0f)) {
      const float mnew = fmaxf(m_, pmax);
      const float scl = exp2f(m_ - mnew);
      m_ = mnew;
      l_ *= scl;
#pragma unroll
      for (int r = 0; r < 16; ++r) {
        const float sr = __shfl(scl, ((r & 3) + 8 * (r >> 2)) + 4 * hi);
        o0[r] *= sr;
        o1[r] *= sr;
      }
    }

    float p0[16], p1[16];
#pragma unroll
    for (int i = 0; i < 16; ++i) p0[i] = exp2f(s0[i] - m_);
#pragma unroll
    for (int i = 0; i < 16; ++i) p1[i] = exp2f(s1[i] - m_);
    float ps = 0.f;
    {
      float t0a = 0.f, t1a = 0.f, t2a = 0.f, t3a = 0.f;
#pragma unroll
      for (int i = 0; i < 16; i += 4) {
        t0a += p0[i] + p1[i];
        t1a += p0[i + 1] + p1[i + 1];
        t2a += p0[i + 2] + p1[i + 2];
        t3a += p0[i + 3] + p1[i + 3];
      }
      ps = (t0a + t1a) + (t2a + t3a);
    }
    ps += __shfl_xor(ps, 32);
    l_ += ps;

    // ---- P -> A-fragments (q = lq row-local) + PV ----
    // frag for kc2=c: words {hi?sy1:x1, hi?sy2:x2, hi?y1:sx1, hi?y2:sx2}
    union {
      unsigned u[4];
      bf16x8 v;
    } pa;

#define MAKE_PA(PARR, CC)                                            \
  {                                                                  \
    unsigned x1 = cvtpk_bf16(PARR[(CC)*8 + 0], PARR[(CC)*8 + 1]);    \
    unsigned x2 = cvtpk_bf16(PARR[(CC)*8 + 2], PARR[(CC)*8 + 3]);    \
    unsigned y1 = cvtpk_bf16(PARR[(CC)*8 + 4], PARR[(CC)*8 + 5]);    \
    unsigned y2 = cvtpk_bf16(PARR[(CC)*8 + 6], PARR[(CC)*8 + 7]);    \
    unsigned sx1 = (unsigned)__shfl_xor((int)x1, 32);                \
    unsigned sx2 = (unsigned)__shfl_xor((int)x2, 32);                \
    unsigned sy1 = (unsigned)__shfl_xor((int)y1, 32);                \
    unsigned sy2 = (unsigned)__shfl_xor((int)y2, 32);                \
    pa.u[0] = hi ? sy1 : x1;                                         \
    pa.u[1] = hi ? sy2 : x2;                                         \
    pa.u[2] = hi ? y1 : sx1;                                         \
    pa.u[3] = hi ? y2 : sx2;                                         \
  }

#define PV_STEP(CIDX)                                                         \
  {                                                                           \
    const int slot = (CIDX)*2 + hi;                                           \
    bf16x8 v0 = *(const bf16x8*)((const char*)vs_u + lq * 128 +               \
                                 ((slot ^ (lq & 7)) << 4));                   \
    bf16x8 v1 = *(const bf16x8*)((const char*)vs_u + (32 + lq) * 128 +        \
                                 ((slot ^ (lq & 7)) << 4));                   \
    o0 = __builtin_amdgcn_mfma_f32_32x32x16_bf16(pa.v, v0, o0, 0, 0, 0);      \
    o1 = __builtin_amdgcn_mfma_f32_32x32x16_bf16(pa.v, v1, o1, 0, 0, 0);      \
  }

    MAKE_PA(p0, 0) PV_STEP(0)
    MAKE_PA(p0, 1) PV_STEP(1)
    MAKE_PA(p1, 0) PV_STEP(2)
    MAKE_PA(p1, 1) PV_STEP(3)
#undef MAKE_PA
#undef PV_STEP
  }

  // ---- epilogue: O[q][d] / l_[q], bf16 store ----
  const float linv = 1.0f / l_;
#pragma unroll
  for (int r = 0; r < 16; ++r) {
    const int crow = ((r & 3) + 8 * (r >> 2)) + 4 * hi;
    const float lr = __shfl(linv, crow);
    const int qg = q0 + crow;
    const size_t base = ((size_t)b * S_ + qg) * D_ + h * DK_;
    ctxb[base + lq] = f2bf(o0[r] * lr);
    ctxb[base + 32 + lq] = f2bf(o1[r] * lr);
  }
}

// ---------------------------------------------------------------------------
// Kernel 3a: Wo fp32 [K][N] -> WoT bf16 [N][K]
// ---------------------------------------------------------------------------
__global__ __launch_bounds__(256) void wo_transpose(
    const float* __restrict__ Wo, unsigned short* __restrict__ WoT) {
  __shared__ float t[64][65];
  const int k0 = blockIdx.x * 64, n0 = blockIdx.y * 64;
  const int r = threadIdx.x >> 4, c4 = threadIdx.x & 15;
#pragma unroll
  for (int i = 0; i < 4; ++i) {
    float4 v = *(const float4*)&Wo[(size_t)(k0 + r + 16 * i) * D_ + n0 + c4 * 4];
    t[r + 16 * i][c4 * 4 + 0] = v.x;
    t[r + 16 * i][c4 * 4 + 1] = v.y;
    t[r + 16 * i][c4 * 4 + 2] = v.z;
    t[r + 16 * i][c4 * 4 + 3] = v.w;
  }
  __syncthreads();
  const int n = threadIdx.x >> 2, kc = threadIdx.x & 3;
  union {
    unsigned short u[16];
    uint4 v[2];
  } pk;
#pragma unroll
  for (int j = 0; j < 16; ++j) pk.u[j] = f2bf(t[kc * 16 + j][n]);
  unsigned short* op = WoT + (size_t)(n0 + n) * D_ + k0 + kc * 16;
  *(uint4*)op = pk.v[0];
  *(uint4*)(op + 8) = pk.v[1];
}

// ---------------------------------------------------------------------------
// Kernel 3b: out[4096,1024] = ctx_bf16 @ WoT^T + bo, bf16 MFMA, fp32 out.
// ---------------------------------------------------------------------------
__global__ __launch_bounds__(256) void out_gemm_mfma(
    const unsigned short* __restrict__ A,   // [4096][1024] bf16
    const unsigned short* __restrict__ BT,  // [1024][1024] bf16 = Wo^T
    const float* __restrict__ bo, float* __restrict__ C) {
  __shared__ __align__(16) unsigned short As[128 * 64];  // 16KB
  __shared__ __align__(16) unsigned short Bs[128 * 64];  // 16KB

  const int tid = threadIdx.x;
  const int w = tid >> 6, l = tid & 63;
  const int ll = l & 15, lg = l >> 4;
  const int wr = w >> 1, wc = w & 1;
  const int m0 = blockIdx.y * 128, n0 = blockIdx.x * 128;

  const int srow = l >> 3;
  const int sslot = (l & 7) ^ srow;
  const int g_off = sslot * 8;

  f32x4 acc[4][4];
#pragma unroll
  for (int mt = 0; mt < 4; ++mt)
#pragma unroll
    for (int nt = 0; nt < 4; ++nt) acc[mt][nt] = (f32x4){0.f, 0.f, 0.f, 0.f};

  for (int k0 = 0; k0 < D_; k0 += 64) {
    __syncthreads();
#pragma unroll
    for (int c = 0; c < 4; ++c) {
      const int row = c * 32 + w * 8 + srow;
      load16_lds(A + (size_t)(m0 + row) * D_ + k0 + g_off,
                 (char*)As + c * 4096 + w * 1024);
      load16_lds(BT + (size_t)(n0 + row) * D_ + k0 + g_off,
                 (char*)Bs + c * 4096 + w * 1024);
    }
    __syncthreads();

#pragma unroll
    for (int half = 0; half < 2; ++half) {
      bf16x8 af[4], bfr[4];
#pragma unroll
      for (int mt = 0; mt < 4; ++mt) {
        const int row = wr * 64 + mt * 16 + ll;
        af[mt] = *(const bf16x8*)((const char*)As + row * 128 +
                                  (((half * 4 + lg) ^ (row & 7)) << 4));
      }
#pragma unroll
      for (int nt = 0; nt < 4; ++nt) {
        const int rowb = wc * 64 + nt * 16 + ll;
        bfr[nt] = *(const bf16x8*)((const char*)Bs + rowb * 128 +
                                   (((half * 4 + lg) ^ (rowb & 7)) << 4));
      }
#pragma unroll
      for (int mt = 0; mt < 4; ++mt)
#pragma unroll
        for (int nt = 0; nt < 4; ++nt)
          acc[mt][nt] = __builtin_amdgcn_mfma_f32_16x16x32_bf16(
              af[mt], bfr[nt], acc[mt][nt], 0, 0, 0);
    }
  }

#pragma unroll
  for (int nt = 0; nt < 4; ++nt) {
    const int col = n0 + wc * 64 + nt * 16 + ll;
    const float bv = bo[col];
#pragma unroll
    for (int mt = 0; mt < 4; ++mt) {
      const int row0 = m0 + wr * 64 + mt * 16 + lg * 4;
#pragma unroll
      for (int r = 0; r < 4; ++r)
        C[(size_t)(row0 + r) * D_ + col] = acc[mt][nt][r] + bv;
    }
  }
}

// ---------------------------------------------------------------------------
extern "C" void kernel_launch(void* const* d_in, const int* in_sizes, int n_in,
                              void* d_out, int out_size, void* d_ws,
                              size_t ws_size, hipStream_t stream) {
  const float* q = (const float*)d_in[0];
  const float* k = (const float*)d_in[1];
  const float* v = (const float*)d_in[2];
  const float* Wq1 = (const float*)d_in[3];
  const float* bq1 = (const float*)d_in[4];
  const float* Wq2 = (const float*)d_in[5];
  const float* bq2 = (const float*)d_in[6];
  const float* Wk1 = (const float*)d_in[7];
  const float* bk1 = (const float*)d_in[8];
  const float* Wk2 = (const float*)d_in[9];
  const float* bk2 = (const float*)d_in[10];
  const float* Wv1 = (const float*)d_in[11];
  const float* bv1 = (const float*)d_in[12];
  const float* Wv2 = (const float*)d_in[13];
  const float* bv2 = (const float*)d_in[14];
  const float* Wo = (const float*)d_in[15];
  const float* bo = (const float*)d_in[16];
  float* out = (float*)d_out;

  const size_t TEN = (size_t)B_ * H_ * S_ * DK_;  // 4,194,304 elements
  char* ws = (char*)d_ws;
  unsigned short* qhb = (unsigned short*)ws;              // bf16 [BH,S,DK]
  unsigned short* khb = (unsigned short*)(ws + TEN * 2);  // bf16 [BH,S,DK]
  unsigned short* vtb = (unsigned short*)(ws + TEN * 4);  // bf16 [BH,DK,S]
  unsigned short* ctxb = (unsigned short*)(ws + TEN * 6); // bf16 [B,S,D]
  unsigned short* wot = (unsigned short*)(ws + TEN * 8);  // bf16 [N,K] = Wo^T

  const float cs = 0.125f * 1.44269504088896340736f;  // 1/sqrt(64) * log2(e)
  quantum_kernel<<<dim3(2048), 256, 0, stream>>>(q, Wq1, bq1, Wq2, bq2, qhb, cs);
  quantum_kernel<<<dim3(2048), 256, 0, stream>>>(k, Wk1, bk1, Wk2, bk2, khb, 1.0f);
  quantum_v_kernel<<<dim3(32, 32), 256, 0, stream>>>(v, Wv1, bv1, Wv2, bv2, vtb);
  wo_transpose<<<dim3(16, 16), 256, 0, stream>>>(Wo, wot);

  attn_kernel<<<dim3(32, 16), 256, 0, stream>>>(qhb, khb, vtb, ctxb);

  out_gemm_mfma<<<dim3(8, 32), 256, 0, stream>>>(ctxb, wot, bo, out);
}

// Round 5
// 116.616 us; speedup vs baseline: 12.5588x; 2.4650x over previous
//
#include <hip/hip_runtime.h>

#define B_ 2
#define S_ 2048
#define D_ 1024
#define H_ 16
#define DK_ 64

typedef float f32x4 __attribute__((ext_vector_type(4)));
typedef float f32x16 __attribute__((ext_vector_type(16)));
typedef short bf16x8 __attribute__((ext_vector_type(8)));

static __device__ __forceinline__ unsigned short f2bf(float f) {
  unsigned u = __float_as_uint(f);
  unsigned r = (u + 0x7FFFu + ((u >> 16) & 1u)) >> 16;
  return (unsigned short)r;
}

static __device__ __forceinline__ unsigned cvtpk_bf16(float lo, float hi) {
  unsigned r;
  asm("v_cvt_pk_bf16_f32 %0, %1, %2" : "=v"(r) : "v"(lo), "v"(hi));
  return r;
}

static __device__ __forceinline__ void load16_lds(const void* g, void* lds) {
  __builtin_amdgcn_global_load_lds(
      (const __attribute__((address_space(1))) unsigned int*)g,
      (__attribute__((address_space(3))) unsigned int*)lds, 16, 0, 0);
}

// gather 8 consecutive C-rows of this lane's owned column from crow-scattered
// accumulator regs p[0..7]; returns the 8 bf16 packed (A-frag k-slice).
// hi0 lane -> rows 0..7, hi1 lane -> rows 8..15 of the 16-row slice.
static __device__ __forceinline__ bf16x8 make_pa8(const float* p, int hi) {
  unsigned x1 = cvtpk_bf16(p[0], p[1]);
  unsigned x2 = cvtpk_bf16(p[2], p[3]);
  unsigned y1 = cvtpk_bf16(p[4], p[5]);
  unsigned y2 = cvtpk_bf16(p[6], p[7]);
  unsigned sx1 = (unsigned)__shfl_xor((int)x1, 32);
  unsigned sx2 = (unsigned)__shfl_xor((int)x2, 32);
  unsigned sy1 = (unsigned)__shfl_xor((int)y1, 32);
  unsigned sy2 = (unsigned)__shfl_xor((int)y2, 32);
  union {
    unsigned u[4];
    bf16x8 v;
  } pa;
  pa.u[0] = hi ? sy1 : x1;
  pa.u[1] = hi ? sy2 : x2;
  pa.u[2] = hi ? y1 : sx1;
  pa.u[3] = hi ? y2 : sx2;
  return pa.v;
}

static __device__ __forceinline__ float tanh_fast(float x) {
  float xc = fminf(fmaxf(x, -9.0f), 9.0f);
  float e = exp2f(xc * 2.88539008177792681472f);  // 2*log2(e)
  return (e - 1.0f) / (e + 1.0f);
}

// ---------------------------------------------------------------------------
// Kernel 1: fused MFMA quantum transform for q, k, v (blockIdx.z selects).
// x: fp32 [B,S,H,DK]. q/k out: bf16 [BH,S,DK] (q pre-scaled); v out: [BH,DK,S].
// Per wave: 32 rows (same b,h; consecutive s).
//   Phase1 (swapped): acc1 = W1^T @ X^T  (lane owns X-row = lane&31)
//   tanh lane-local; MAKE_PA -> A-frags; Phase2: Y = T @ W2.
// grid (16 s-groups of 128, 32 bh, 3 tensors), block 256.
// ---------------------------------------------------------------------------
__global__ __launch_bounds__(256) void quantum_fused(
    const float* __restrict__ xq, const float* __restrict__ xk,
    const float* __restrict__ xv,
    const float* __restrict__ Wq1, const float* __restrict__ bq1,
    const float* __restrict__ Wq2, const float* __restrict__ bq2,
    const float* __restrict__ Wk1, const float* __restrict__ bk1,
    const float* __restrict__ Wk2, const float* __restrict__ bk2,
    const float* __restrict__ Wv1, const float* __restrict__ bv1,
    const float* __restrict__ Wv2, const float* __restrict__ bv2,
    unsigned short* __restrict__ qhb, unsigned short* __restrict__ khb,
    unsigned short* __restrict__ vtb, float qscale) {
  const int tid = threadIdx.x;
  const int w = tid >> 6;
  const int l = tid & 63;
  const int lq = l & 31;
  const int hi = l >> 5;
  const int bh = blockIdx.y;
  const int b = bh >> 4, h = bh & 15;
  const int s0w = blockIdx.x * 128 + w * 32;

  const float* x;
  const float* W1;
  const float* b1;
  const float* W2;
  const float* b2;
  unsigned short* outp;
  float scale = 1.0f;
  int vmode = 0;
  if (blockIdx.z == 0) {
    x = xq; W1 = Wq1; b1 = bq1; W2 = Wq2; b2 = bq2; outp = qhb;
    scale = qscale;
  } else if (blockIdx.z == 1) {
    x = xk; W1 = Wk1; b1 = bk1; W2 = Wk2; b2 = bk2; outp = khb;
  } else {
    x = xv; W1 = Wv1; b1 = bv1; W2 = Wv2; b2 = bv2; outp = vtb;
    vmode = 1;
  }

  // ---- W1^T A-frags: w1f[ca][kc][j] = W1[kc*16+hi*8+j][ca*32+lq] ----
  bf16x8 w1f[2][4];
#pragma unroll
  for (int ca = 0; ca < 2; ++ca)
#pragma unroll
    for (int kc = 0; kc < 4; ++kc) {
      const float* wp = W1 + (size_t)(kc * 16 + hi * 8) * 64 + ca * 32 + lq;
      union {
        unsigned u[4];
        bf16x8 v;
      } ww;
#pragma unroll
      for (int jj = 0; jj < 4; ++jj)
        ww.u[jj] = cvtpk_bf16(wp[(2 * jj) * 64], wp[(2 * jj + 1) * 64]);
      w1f[ca][kc] = ww.v;
    }

  // ---- X^T B-frags: xf[kc][j] = X[row=s0w+lq][kc*16+hi*8+j] (bf16) ----
  const float* xrow = x + (((size_t)b * S_ + s0w + lq) * H_ + h) * DK_;
  bf16x8 xf[4];
#pragma unroll
  for (int kc = 0; kc < 4; ++kc) {
    float4 f0 = *(const float4*)(xrow + kc * 16 + hi * 8);
    float4 f1 = *(const float4*)(xrow + kc * 16 + hi * 8 + 4);
    union {
      unsigned u[4];
      bf16x8 v;
    } xx;
    xx.u[0] = cvtpk_bf16(f0.x, f0.y);
    xx.u[1] = cvtpk_bf16(f0.z, f0.w);
    xx.u[2] = cvtpk_bf16(f1.x, f1.y);
    xx.u[3] = cvtpk_bf16(f1.z, f1.w);
    xf[kc] = xx.v;
  }

  // ---- phase 1: acc1[ca] = b1 + W1^T @ X^T ----
  f32x16 acc1[2];
#pragma unroll
  for (int ca = 0; ca < 2; ++ca)
#pragma unroll
    for (int r = 0; r < 16; ++r)
      acc1[ca][r] = b1[ca * 32 + (r & 3) + 8 * (r >> 2) + 4 * hi];
#pragma unroll
  for (int kc = 0; kc < 4; ++kc) {
    acc1[0] = __builtin_amdgcn_mfma_f32_32x32x16_bf16(w1f[0][kc], xf[kc], acc1[0], 0, 0, 0);
    acc1[1] = __builtin_amdgcn_mfma_f32_32x32x16_bf16(w1f[1][kc], xf[kc], acc1[1], 0, 0, 0);
  }

  // ---- tanh (lane-local; lane owns row lq, regs span T-cols) ----
  float t0[16], t1[16];
#pragma unroll
  for (int r = 0; r < 16; ++r) {
    t0[r] = tanh_fast(acc1[0][r]);
    t1[r] = tanh_fast(acc1[1][r]);
  }

  // ---- T A-frags via make_pa8 (k-slices of 16 T-cols) ----
  bf16x8 af[4];
  af[0] = make_pa8(&t0[0], hi);
  af[1] = make_pa8(&t0[8], hi);
  af[2] = make_pa8(&t1[0], hi);
  af[3] = make_pa8(&t1[8], hi);

  // ---- W2 B-frags: w2f[nb][kc][j] = W2[kc*16+hi*8+j][nb*32+lq] ----
  bf16x8 w2f[2][4];
#pragma unroll
  for (int nb = 0; nb < 2; ++nb)
#pragma unroll
    for (int kc = 0; kc < 4; ++kc) {
      const float* wp = W2 + (size_t)(kc * 16 + hi * 8) * 64 + nb * 32 + lq;
      union {
        unsigned u[4];
        bf16x8 v;
      } ww;
#pragma unroll
      for (int jj = 0; jj < 4; ++jj)
        ww.u[jj] = cvtpk_bf16(wp[(2 * jj) * 64], wp[(2 * jj + 1) * 64]);
      w2f[nb][kc] = ww.v;
    }

  // ---- phase 2: acc2[nb] = b2 + T @ W2 ----
  f32x16 acc2[2];
#pragma unroll
  for (int nb = 0; nb < 2; ++nb)
#pragma unroll
    for (int r = 0; r < 16; ++r)
      acc2[nb][r] = b2[nb * 32 + (r & 3) + 8 * (r >> 2) + 4 * hi];
#pragma unroll
  for (int kc = 0; kc < 4; ++kc) {
    acc2[0] = __builtin_amdgcn_mfma_f32_32x32x16_bf16(af[kc], w2f[0][kc], acc2[0], 0, 0, 0);
    acc2[1] = __builtin_amdgcn_mfma_f32_32x32x16_bf16(af[kc], w2f[1][kc], acc2[1], 0, 0, 0);
  }

  // ---- store ----
  if (!vmode) {
    // row-major [bh][s][d]: lane owns col d=nb*32+lq, regs span s
#pragma unroll
    for (int nb = 0; nb < 2; ++nb)
#pragma unroll
      for (int r = 0; r < 16; ++r) {
        const int s = s0w + (r & 3) + 8 * (r >> 2) + 4 * hi;
        outp[((size_t)bh * S_ + s) * DK_ + nb * 32 + lq] =
            f2bf(acc2[nb][r] * scale);
      }
  } else {
    // transposed [bh][d][s]: make_pa8 gathers 8 consecutive s of own d col
#pragma unroll
    for (int nb = 0; nb < 2; ++nb) {
      float yv[16];
#pragma unroll
      for (int r = 0; r < 16; ++r) yv[r] = acc2[nb][r];
      const size_t rowb = ((size_t)bh * DK_ + nb * 32 + lq) * S_;
      *(bf16x8*)(outp + rowb + s0w + hi * 8) = make_pa8(&yv[0], hi);
      *(bf16x8*)(outp + rowb + s0w + 16 + hi * 8) = make_pa8(&yv[8], hi);
    }
  }
}

// ---------------------------------------------------------------------------
// Kernel 2: MFMA flash attention, swapped-QK^T 32x32x16 structure.
// ---------------------------------------------------------------------------
__global__ __launch_bounds__(256, 2) void attn_kernel(
    const unsigned short* __restrict__ qhb,
    const unsigned short* __restrict__ khb,
    const unsigned short* __restrict__ vtb,
    unsigned short* __restrict__ ctxb) {
  __shared__ __align__(16) unsigned short ks_u[64 * 64];  // [key][d] swizzled
  __shared__ __align__(16) unsigned short vs_u[64 * 64];  // [d][key] swizzled

  const int tid = threadIdx.x;
  const int w = tid >> 6;
  const int l = tid & 63;
  const int lq = l & 31;
  const int hi = l >> 5;
  const int bh = blockIdx.x;
  const int b = bh >> 4, h = bh & 15;
  const int q0 = blockIdx.y * 128 + w * 32;

  const unsigned short* qp = qhb + ((size_t)bh * S_ + q0 + lq) * DK_ + hi * 8;
  bf16x8 qf[4];
#pragma unroll
  for (int kc = 0; kc < 4; ++kc) qf[kc] = *(const bf16x8*)(qp + kc * 16);

  f32x16 o0 = {}, o1 = {};
  float m_ = -1e30f, l_ = 0.f;

  const int kk = tid >> 2, ch = tid & 3;
  const unsigned short* kgbase = khb + (size_t)bh * S_ * DK_;
  const unsigned short* vgbase = vtb + (size_t)bh * DK_ * S_;

  for (int t0 = 0; t0 < S_; t0 += 64) {
    __syncthreads();
    {
      const uint4* gk = (const uint4*)(kgbase + ((size_t)(t0 + kk)) * DK_ + ch * 16);
      uint4 a0 = gk[0];
      uint4 a1 = gk[1];
      char* kd = (char*)ks_u + kk * 128;
      *(uint4*)(kd + (((ch * 2 + 0) ^ (kk & 7)) << 4)) = a0;
      *(uint4*)(kd + (((ch * 2 + 1) ^ (kk & 7)) << 4)) = a1;

      const uint4* gv = (const uint4*)(vgbase + ((size_t)kk) * S_ + t0 + ch * 16);
      uint4 b0 = gv[0];
      uint4 b1 = gv[1];
      char* vd = (char*)vs_u + kk * 128;
      *(uint4*)(vd + (((ch * 2 + 0) ^ (kk & 7)) << 4)) = b0;
      *(uint4*)(vd + (((ch * 2 + 1) ^ (kk & 7)) << 4)) = b1;
    }
    __syncthreads();

    f32x16 s0 = {}, s1 = {};
#pragma unroll
    for (int kc = 0; kc < 4; ++kc) {
      const int slot = kc * 2 + hi;
      bf16x8 k0 = *(const bf16x8*)((const char*)ks_u + lq * 128 +
                                   ((slot ^ (lq & 7)) << 4));
      bf16x8 k1 = *(const bf16x8*)((const char*)ks_u + (32 + lq) * 128 +
                                   ((slot ^ (lq & 7)) << 4));
      s0 = __builtin_amdgcn_mfma_f32_32x32x16_bf16(k0, qf[kc], s0, 0, 0, 0);
      s1 = __builtin_amdgcn_mfma_f32_32x32x16_bf16(k1, qf[kc], s1, 0, 0, 0);
    }

    float pmax = s0[0];
#pragma unroll
    for (int i = 1; i < 16; ++i) pmax = fmaxf(pmax, s0[i]);
#pragma unroll
    for (int i = 0; i < 16; ++i) pmax = fmaxf(pmax, s1[i]);
    pmax = fmaxf(pmax, __shfl_xor(pmax, 32));

    if (!__all(pmax <= m_ + 8.0f)) {
      const float mnew = fmaxf(m_, pmax);
      const float scl = exp2f(m_ - mnew);
      m_ = mnew;
      l_ *= scl;
#pragma unroll
      for (int r = 0; r < 16; ++r) {
        const float sr = __shfl(scl, ((r & 3) + 8 * (r >> 2)) + 4 * hi);
        o0[r] *= sr;
        o1[r] *= sr;
      }
    }

    float p0[16], p1[16];
#pragma unroll
    for (int i = 0; i < 16; ++i) p0[i] = exp2f(s0[i] - m_);
#pragma unroll
    for (int i = 0; i < 16; ++i) p1[i] = exp2f(s1[i] - m_);
    float ps = 0.f;
    {
      float t0a = 0.f, t1a = 0.f, t2a = 0.f, t3a = 0.f;
#pragma unroll
      for (int i = 0; i < 16; i += 4) {
        t0a += p0[i] + p1[i];
        t1a += p0[i + 1] + p1[i + 1];
        t2a += p0[i + 2] + p1[i + 2];
        t3a += p0[i + 3] + p1[i + 3];
      }
      ps = (t0a + t1a) + (t2a + t3a);
    }
    ps += __shfl_xor(ps, 32);
    l_ += ps;

    union {
      unsigned u[4];
      bf16x8 v;
    } pa;

#define MAKE_PA(PARR, CC)                                            \
  {                                                                  \
    unsigned x1 = cvtpk_bf16(PARR[(CC)*8 + 0], PARR[(CC)*8 + 1]);    \
    unsigned x2 = cvtpk_bf16(PARR[(CC)*8 + 2], PARR[(CC)*8 + 3]);    \
    unsigned y1 = cvtpk_bf16(PARR[(CC)*8 + 4], PARR[(CC)*8 + 5]);    \
    unsigned y2 = cvtpk_bf16(PARR[(CC)*8 + 6], PARR[(CC)*8 + 7]);    \
    unsigned sx1 = (unsigned)__shfl_xor((int)x1, 32);                \
    unsigned sx2 = (unsigned)__shfl_xor((int)x2, 32);                \
    unsigned sy1 = (unsigned)__shfl_xor((int)y1, 32);                \
    unsigned sy2 = (unsigned)__shfl_xor((int)y2, 32);                \
    pa.u[0] = hi ? sy1 : x1;                                         \
    pa.u[1] = hi ? sy2 : x2;                                         \
    pa.u[2] = hi ? y1 : sx1;                                         \
    pa.u[3] = hi ? y2 : sx2;                                         \
  }

#define PV_STEP(CIDX)                                                         \
  {                                                                           \
    const int slot = (CIDX)*2 + hi;                                           \
    bf16x8 v0 = *(const bf16x8*)((const char*)vs_u + lq * 128 +               \
                                 ((slot ^ (lq & 7)) << 4));                   \
    bf16x8 v1 = *(const bf16x8*)((const char*)vs_u + (32 + lq) * 128 +        \
                                 ((slot ^ (lq & 7)) << 4));                   \
    o0 = __builtin_amdgcn_mfma_f32_32x32x16_bf16(pa.v, v0, o0, 0, 0, 0);      \
    o1 = __builtin_amdgcn_mfma_f32_32x32x16_bf16(pa.v, v1, o1, 0, 0, 0);      \
  }

    MAKE_PA(p0, 0) PV_STEP(0)
    MAKE_PA(p0, 1) PV_STEP(1)
    MAKE_PA(p1, 0) PV_STEP(2)
    MAKE_PA(p1, 1) PV_STEP(3)
#undef MAKE_PA
#undef PV_STEP
  }

  const float linv = 1.0f / l_;
#pragma unroll
  for (int r = 0; r < 16; ++r) {
    const int crow = ((r & 3) + 8 * (r >> 2)) + 4 * hi;
    const float lr = __shfl(linv, crow);
    const int qg = q0 + crow;
    const size_t base = ((size_t)b * S_ + qg) * D_ + h * DK_;
    ctxb[base + lq] = f2bf(o0[r] * lr);
    ctxb[base + 32 + lq] = f2bf(o1[r] * lr);
  }
}

// ---------------------------------------------------------------------------
// Kernel 3a: Wo fp32 [K][N] -> WoT bf16 [N][K]
// ---------------------------------------------------------------------------
__global__ __launch_bounds__(256) void wo_transpose(
    const float* __restrict__ Wo, unsigned short* __restrict__ WoT) {
  __shared__ float t[64][65];
  const int k0 = blockIdx.x * 64, n0 = blockIdx.y * 64;
  const int r = threadIdx.x >> 4, c4 = threadIdx.x & 15;
#pragma unroll
  for (int i = 0; i < 4; ++i) {
    float4 v = *(const float4*)&Wo[(size_t)(k0 + r + 16 * i) * D_ + n0 + c4 * 4];
    t[r + 16 * i][c4 * 4 + 0] = v.x;
    t[r + 16 * i][c4 * 4 + 1] = v.y;
    t[r + 16 * i][c4 * 4 + 2] = v.z;
    t[r + 16 * i][c4 * 4 + 3] = v.w;
  }
  __syncthreads();
  const int n = threadIdx.x >> 2, kc = threadIdx.x & 3;
  union {
    unsigned short u[16];
    uint4 v[2];
  } pk;
#pragma unroll
  for (int j = 0; j < 16; ++j) pk.u[j] = f2bf(t[kc * 16 + j][n]);
  unsigned short* op = WoT + (size_t)(n0 + n) * D_ + k0 + kc * 16;
  *(uint4*)op = pk.v[0];
  *(uint4*)(op + 8) = pk.v[1];
}

// ---------------------------------------------------------------------------
// Kernel 3b: out[4096,1024] = ctx_bf16 @ WoT^T + bo, bf16 MFMA, fp32 out.
// ---------------------------------------------------------------------------
__global__ __launch_bounds__(256) void out_gemm_mfma(
    const unsigned short* __restrict__ A,
    const unsigned short* __restrict__ BT,
    const float* __restrict__ bo, float* __restrict__ C) {
  __shared__ __align__(16) unsigned short As[128 * 64];
  __shared__ __align__(16) unsigned short Bs[128 * 64];

  const int tid = threadIdx.x;
  const int w = tid >> 6, l = tid & 63;
  const int ll = l & 15, lg = l >> 4;
  const int wr = w >> 1, wc = w & 1;
  const int m0 = blockIdx.y * 128, n0 = blockIdx.x * 128;

  const int srow = l >> 3;
  const int sslot = (l & 7) ^ srow;
  const int g_off = sslot * 8;

  f32x4 acc[4][4];
#pragma unroll
  for (int mt = 0; mt < 4; ++mt)
#pragma unroll
    for (int nt = 0; nt < 4; ++nt) acc[mt][nt] = (f32x4){0.f, 0.f, 0.f, 0.f};

  for (int k0 = 0; k0 < D_; k0 += 64) {
    __syncthreads();
#pragma unroll
    for (int c = 0; c < 4; ++c) {
      const int row = c * 32 + w * 8 + srow;
      load16_lds(A + (size_t)(m0 + row) * D_ + k0 + g_off,
                 (char*)As + c * 4096 + w * 1024);
      load16_lds(BT + (size_t)(n0 + row) * D_ + k0 + g_off,
                 (char*)Bs + c * 4096 + w * 1024);
    }
    __syncthreads();

#pragma unroll
    for (int half = 0; half < 2; ++half) {
      bf16x8 af[4], bfr[4];
#pragma unroll
      for (int mt = 0; mt < 4; ++mt) {
        const int row = wr * 64 + mt * 16 + ll;
        af[mt] = *(const bf16x8*)((const char*)As + row * 128 +
                                  (((half * 4 + lg) ^ (row & 7)) << 4));
      }
#pragma unroll
      for (int nt = 0; nt < 4; ++nt) {
        const int rowb = wc * 64 + nt * 16 + ll;
        bfr[nt] = *(const bf16x8*)((const char*)Bs + rowb * 128 +
                                   (((half * 4 + lg) ^ (rowb & 7)) << 4));
      }
#pragma unroll
      for (int mt = 0; mt < 4; ++mt)
#pragma unroll
        for (int nt = 0; nt < 4; ++nt)
          acc[mt][nt] = __builtin_amdgcn_mfma_f32_16x16x32_bf16(
              af[mt], bfr[nt], acc[mt][nt], 0, 0, 0);
    }
  }

#pragma unroll
  for (int nt = 0; nt < 4; ++nt) {
    const int col = n0 + wc * 64 + nt * 16 + ll;
    const float bv = bo[col];
#pragma unroll
    for (int mt = 0; mt < 4; ++mt) {
      const int row0 = m0 + wr * 64 + mt * 16 + lg * 4;
#pragma unroll
      for (int r = 0; r < 4; ++r)
        C[(size_t)(row0 + r) * D_ + col] = acc[mt][nt][r] + bv;
    }
  }
}

// ---------------------------------------------------------------------------
extern "C" void kernel_launch(void* const* d_in, const int* in_sizes, int n_in,
                              void* d_out, int out_size, void* d_ws,
                              size_t ws_size, hipStream_t stream) {
  const float* q = (const float*)d_in[0];
  const float* k = (const float*)d_in[1];
  const float* v = (const float*)d_in[2];
  const float* Wq1 = (const float*)d_in[3];
  const float* bq1 = (const float*)d_in[4];
  const float* Wq2 = (const float*)d_in[5];
  const float* bq2 = (const float*)d_in[6];
  const float* Wk1 = (const float*)d_in[7];
  const float* bk1 = (const float*)d_in[8];
  const float* Wk2 = (const float*)d_in[9];
  const float* bk2 = (const float*)d_in[10];
  const float* Wv1 = (const float*)d_in[11];
  const float* bv1 = (const float*)d_in[12];
  const float* Wv2 = (const float*)d_in[13];
  const float* bv2 = (const float*)d_in[14];
  const float* Wo = (const float*)d_in[15];
  const float* bo = (const float*)d_in[16];
  float* out = (float*)d_out;

  const size_t TEN = (size_t)B_ * H_ * S_ * DK_;  // 4,194,304 elements
  char* ws = (char*)d_ws;
  unsigned short* qhb = (unsigned short*)ws;              // bf16 [BH,S,DK]
  unsigned short* khb = (unsigned short*)(ws + TEN * 2);  // bf16 [BH,S,DK]
  unsigned short* vtb = (unsigned short*)(ws + TEN * 4);  // bf16 [BH,DK,S]
  unsigned short* ctxb = (unsigned short*)(ws + TEN * 6); // bf16 [B,S,D]
  unsigned short* wot = (unsigned short*)(ws + TEN * 8);  // bf16 [N,K] = Wo^T

  const float cs = 0.125f * 1.44269504088896340736f;  // 1/sqrt(64) * log2(e)
  quantum_fused<<<dim3(16, 32, 3), 256, 0, stream>>>(
      q, k, v, Wq1, bq1, Wq2, bq2, Wk1, bk1, Wk2, bk2, Wv1, bv1, Wv2, bv2,
      qhb, khb, vtb, cs);
  wo_transpose<<<dim3(16, 16), 256, 0, stream>>>(Wo, wot);

  attn_kernel<<<dim3(32, 16), 256, 0, stream>>>(qhb, khb, vtb, ctxb);

  out_gemm_mfma<<<dim3(8, 32), 256, 0, stream>>>(ctxb, wot, bo, out);
}